// Round 2
// baseline (2598.076 us; speedup 1.0000x reference)
//
#include <hip/hip_runtime.h>
#include <hip/hip_bf16.h>
#include <math.h>

// ---------------- problem constants ----------------
#define Dm    512
#define Hh    8
#define NLay  6
#define DFFm  2048
#define Bb    4
#define NTOK  2048          // B * S
#define PADID 1
#define LNEPS 1e-5f

typedef __attribute__((ext_vector_type(8))) short short8;   // 8 x bf16 (4 VGPRs)
typedef __attribute__((ext_vector_type(4))) float f32x4;
typedef unsigned short u16;

static constexpr long S2  = 512L * 512L;
static constexpr long HS2 = 8L * 512L * 512L;

__device__ __forceinline__ u16 f2bf(float f) {
    union { float f; unsigned int i; } x; x.f = f;
    unsigned int r = x.i + 0x7fffu + ((x.i >> 16) & 1u);   // RNE
    return (u16)(r >> 16);
}

// f32 -> bf16 elementwise (n divisible by 4), grid-stride
__global__ __launch_bounds__(256) void cvt_bf16(
    const float* __restrict__ in, u16* __restrict__ out, long n4)
{
    long i = (long)blockIdx.x * 256 + threadIdx.x;
    long stride = (long)gridDim.x * 256;
    for (; i < n4; i += stride) {
        float4 v = ((const float4*)in)[i];
        ushort4 o;
        o.x = f2bf(v.x); o.y = f2bf(v.y); o.z = f2bf(v.z); o.w = f2bf(v.w);
        ((ushort4*)out)[i] = o;
    }
}

// ---------------------------------------------------------------------------
// Generic bf16 GEMM: C[m,n] = alpha * sum_k A[m,k]*B[n,k]  (+bias[n]) (+res[m,n]) (relu?)
// A: [M,K] bf16 row-major (lda), B: [N,K] bf16 row-major (ldb)  -> A @ B^T
// C written to f32 (Cf) and/or bf16 (Cb) at coff + m*csm + n*csn.
// Batched over grid.z: z -> (zb = z/Z2, zh = z%Z2), per-operand stride pairs.
// Tile 64x64, 4 waves (256 thr), BK=32, mfma_f32_16x16x32_bf16.
// C/D lane map (m89-verified): col = lane&15, row = (lane>>4)*4 + r.
// A/B frag: row (resp. col) = lane&15, k = (lane>>4)*8 + e  (contiguous 8)
// ---------------------------------------------------------------------------
__global__ __launch_bounds__(256) void gemm_bt(
    const u16* __restrict__ A, int lda, long sAb, long sAh,
    const u16* __restrict__ B, int ldb, long sBb, long sBh,
    float* Cf, u16* Cb, int csm, int csn, long sCb, long sCh,
    const float* __restrict__ bias,
    const float* res, int ldres,
    float alpha, int relu, int Z2, int K)
{
    __shared__ u16 As[64][40];   // +8 pad -> 80B rows, ~2-way bank aliasing (free)
    __shared__ u16 Bs[64][40];

    int zb = blockIdx.z, zh = 0;
    if (Z2 > 1) { zb = blockIdx.z / Z2; zh = blockIdx.z % Z2; }
    const u16* Ab = A + zb * sAb + zh * sAh;
    const u16* Bp = B + zb * sBb + zh * sBh;
    long coff = (long)zb * sCb + (long)zh * sCh;

    const int m0 = blockIdx.y << 6;
    const int n0 = blockIdx.x << 6;
    const int t    = threadIdx.x;
    const int lane = t & 63;
    const int wave = t >> 6;
    const int wr = (wave >> 1) << 5;
    const int wc = (wave & 1) << 5;
    const int fr = lane & 15;
    const int fq = lane >> 4;
    const int lrow = t >> 2;
    const int lcol = (t & 3) << 3;

    const u16* Aload = Ab + (long)(m0 + lrow) * lda + lcol;
    const u16* Bload = Bp + (long)(n0 + lrow) * ldb + lcol;

    f32x4 acc[2][2];
    #pragma unroll
    for (int i = 0; i < 2; i++)
        #pragma unroll
        for (int j = 0; j < 2; j++)
            acc[i][j] = (f32x4){0.f, 0.f, 0.f, 0.f};

    for (int k0 = 0; k0 < K; k0 += 32) {
        short8 av = *(const short8*)(Aload + k0);
        short8 bv = *(const short8*)(Bload + k0);
        *(short8*)&As[lrow][lcol] = av;
        *(short8*)&Bs[lrow][lcol] = bv;
        __syncthreads();

        short8 af0 = *(const short8*)&As[wr      + fr][fq << 3];
        short8 af1 = *(const short8*)&As[wr + 16 + fr][fq << 3];
        short8 bf0 = *(const short8*)&Bs[wc      + fr][fq << 3];
        short8 bf1 = *(const short8*)&Bs[wc + 16 + fr][fq << 3];
        acc[0][0] = __builtin_amdgcn_mfma_f32_16x16x32_bf16(af0, bf0, acc[0][0], 0, 0, 0);
        acc[0][1] = __builtin_amdgcn_mfma_f32_16x16x32_bf16(af0, bf1, acc[0][1], 0, 0, 0);
        acc[1][0] = __builtin_amdgcn_mfma_f32_16x16x32_bf16(af1, bf0, acc[1][0], 0, 0, 0);
        acc[1][1] = __builtin_amdgcn_mfma_f32_16x16x32_bf16(af1, bf1, acc[1][1], 0, 0, 0);
        __syncthreads();
    }

    #pragma unroll
    for (int i = 0; i < 2; i++) {
        #pragma unroll
        for (int j = 0; j < 2; j++) {
            int nl  = n0 + wc + (j << 4) + fr;
            int mlb = m0 + wr + (i << 4) + (fq << 2);
            float bsv = bias ? bias[nl] : 0.f;
            #pragma unroll
            for (int r = 0; r < 4; r++) {
                int ml = mlb + r;
                float v = acc[i][j][r] * alpha + bsv;
                if (res)  v += res[(long)ml * ldres + nl];
                if (relu) v = fmaxf(v, 0.f);
                long ci = coff + (long)ml * csm + (long)nl * csn;
                if (Cf) Cf[ci] = v;
                if (Cb) Cb[ci] = f2bf(v);
            }
        }
    }
}

// LayerNorm over D=512: one wave per row. f32 in -> bf16 out. g,b are f32.
__global__ __launch_bounds__(64) void ln_rows(
    const float* __restrict__ x, const float* __restrict__ g,
    const float* __restrict__ b, u16* __restrict__ out)
{
    int row = blockIdx.x;
    int lane = threadIdx.x;
    const float* xr = x + (long)row * Dm;
    float v[8]; float s = 0.f;
    #pragma unroll
    for (int i = 0; i < 8; i++) { v[i] = xr[lane + (i << 6)]; s += v[i]; }
    #pragma unroll
    for (int o = 32; o > 0; o >>= 1) s += __shfl_xor(s, o);
    float mean = s * (1.f / 512.f);
    float q = 0.f;
    #pragma unroll
    for (int i = 0; i < 8; i++) { float d = v[i] - mean; q += d * d; }
    #pragma unroll
    for (int o = 32; o > 0; o >>= 1) q += __shfl_xor(q, o);
    float rinv = rsqrtf(q * (1.f / 512.f) + LNEPS);
    u16* orow = out + (long)row * Dm;
    #pragma unroll
    for (int i = 0; i < 8; i++) {
        int c = lane + (i << 6);
        orow[c] = f2bf((v[i] - mean) * rinv * g[c] + b[c]);
    }
}

// Masked softmax over 512 keys: one wave per (q,h,b) row. f32 scores -> bf16 P.
__global__ __launch_bounds__(64) void softmax_rows(
    const float* __restrict__ S, u16* __restrict__ P,
    const int* __restrict__ ids, int causal)
{
    int qq = blockIdx.x, h = blockIdx.y, b = blockIdx.z;
    long base = ((((long)b * gridDim.y + h) * gridDim.x) + qq) * 512L;
    int lane = threadIdx.x;
    float v[8];
    float mx = -INFINITY;
    #pragma unroll
    for (int i = 0; i < 8; i++) {
        int k = lane + (i << 6);
        bool msk = (ids[b * 512 + k] == PADID) || (causal && k > qq);
        v[i] = msk ? -INFINITY : S[base + k];
        mx = fmaxf(mx, v[i]);
    }
    #pragma unroll
    for (int o = 32; o > 0; o >>= 1) mx = fmaxf(mx, __shfl_xor(mx, o));
    float e[8]; float sum = 0.f;
    #pragma unroll
    for (int i = 0; i < 8; i++) {
        e[i] = (v[i] == -INFINITY) ? 0.f : __expf(v[i] - mx);
        sum += e[i];
    }
    #pragma unroll
    for (int o = 32; o > 0; o >>= 1) sum += __shfl_xor(sum, o);
    float inv = (sum > 0.f) ? 1.f / sum : 0.f;
    #pragma unroll
    for (int i = 0; i < 8; i++) P[base + lane + (i << 6)] = f2bf(e[i] * inv);
}

// x[b,s,:] = embed[id]*sqrt(D) + PE(s,:)   (f32 in/out)
__global__ __launch_bounds__(256) void embed_pe(
    const int* __restrict__ ids, const float* __restrict__ emb,
    float* __restrict__ out)
{
    int idx = blockIdx.x * 256 + threadIdx.x;   // NTOK*512 = 2^20
    int d   = idx & 511;
    int tok = idx >> 9;
    int s   = tok & 511;
    int id  = ids[tok];
    float val = emb[(long)id * Dm + d] * 22.62741699796952f;     // sqrt(512)
    int i2 = d >> 1;
    float dv  = expf((float)(i2 << 1) * (-9.210340371976184f / 512.f));
    float ang = (float)s * dv;
    val += (d & 1) ? cosf(ang) : sinf(ang);
    out[idx] = val;
}

// ---------------------------------------------------------------------------
extern "C" void kernel_launch(void* const* d_in, const int* in_sizes, int n_in,
                              void* d_out, int out_size, void* d_ws, size_t ws_size,
                              hipStream_t stream)
{
    (void)in_sizes; (void)n_in; (void)out_size; (void)ws_size;
    const int*   src       = (const int*)d_in[0];
    const int*   tgt       = (const int*)d_in[1];
    const float* src_embed = (const float*)d_in[2];
    const float* tgt_embed = (const float*)d_in[3];
    const float* f_encW[4] = { (const float*)d_in[4], (const float*)d_in[5],
                               (const float*)d_in[6], (const float*)d_in[7] };
    const float* enc_w1f   = (const float*)d_in[8];
    const float* enc_b1    = (const float*)d_in[9];
    const float* enc_w2f   = (const float*)d_in[10];
    const float* enc_b2    = (const float*)d_in[11];
    const float* enc_ln1g  = (const float*)d_in[12];
    const float* enc_ln1b  = (const float*)d_in[13];
    const float* enc_ln2g  = (const float*)d_in[14];
    const float* enc_ln2b  = (const float*)d_in[15];
    const float* enc_lnfg  = (const float*)d_in[16];
    const float* enc_lnfb  = (const float*)d_in[17];
    const float* f_decW[8] = { (const float*)d_in[18], (const float*)d_in[19],
                               (const float*)d_in[20], (const float*)d_in[21],
                               (const float*)d_in[22], (const float*)d_in[23],
                               (const float*)d_in[24], (const float*)d_in[25] };
    const float* dec_w1f   = (const float*)d_in[26];
    const float* dec_b1    = (const float*)d_in[27];
    const float* dec_w2f   = (const float*)d_in[28];
    const float* dec_b2    = (const float*)d_in[29];
    const float* dec_ln1g  = (const float*)d_in[30];
    const float* dec_ln1b  = (const float*)d_in[31];
    const float* dec_ln2g  = (const float*)d_in[32];
    const float* dec_ln2b  = (const float*)d_in[33];
    const float* dec_ln3g  = (const float*)d_in[34];
    const float* dec_ln3b  = (const float*)d_in[35];
    const float* dec_lnfg  = (const float*)d_in[36];
    const float* dec_lnfb  = (const float*)d_in[37];
    const float* out_Wf    = (const float*)d_in[38];
    const float* out_b     = (const float*)d_in[39];

    // workspace carve (256B aligned)
    char* wp = (char*)d_ws;
    auto carve = [&](size_t nbytes) {
        void* p = (void*)wp; wp += (nbytes + 255) & ~(size_t)255; return p;
    };

    // ---- converted bf16 weights ----
    const long nW  = (long)NLay * Dm * Dm;       // 1.57M
    const long nF  = (long)NLay * DFFm * Dm;     // 6.29M
    const long nO  = 32000L * Dm;                // 16.38M
    u16* encW[4]; u16* decW[8];
    for (int i = 0; i < 4; i++) encW[i] = (u16*)carve(nW * 2);
    u16* enc_w1 = (u16*)carve(nF * 2);
    u16* enc_w2 = (u16*)carve(nF * 2);
    for (int i = 0; i < 8; i++) decW[i] = (u16*)carve(nW * 2);
    u16* dec_w1 = (u16*)carve(nF * 2);
    u16* dec_w2 = (u16*)carve(nF * 2);
    u16* out_W  = (u16*)carve(nO * 2);

    float* x    = (float*)carve((size_t)NTOK * Dm * 4);
    float* y    = (float*)carve((size_t)NTOK * Dm * 4);
    u16* nrm    = (u16*)carve((size_t)NTOK * Dm * 2);
    u16* qb     = (u16*)carve((size_t)NTOK * Dm * 2);
    u16* kb     = (u16*)carve((size_t)NTOK * Dm * 2);
    u16* vt     = (u16*)carve((size_t)Bb * Dm * 512 * 2);     // V^T: [B][h*64+d][s]
    u16* attc   = (u16*)carve((size_t)NTOK * Dm * 2);
    u16* h1     = (u16*)carve((size_t)NTOK * DFFm * 2);
    u16* memn   = (u16*)carve((size_t)NTOK * Dm * 2);
    float* scor = (float*)carve((size_t)Bb * Hh * 512 * 512 * 4);
    u16* pmat   = (u16*)carve((size_t)Bb * Hh * 512 * 512 * 2);

    auto cvt = [&](const float* in, u16* out, long n) {
        long n4 = n >> 2;
        int blocks = (int)((n4 + 255) / 256); if (blocks > 1024) blocks = 1024;
        cvt_bf16<<<blocks, 256, 0, stream>>>(in, out, n4);
    };
    for (int i = 0; i < 4; i++) cvt(f_encW[i], encW[i], nW);
    cvt(enc_w1f, enc_w1, nF);  cvt(enc_w2f, enc_w2, nF);
    for (int i = 0; i < 8; i++) cvt(f_decW[i], decW[i], nW);
    cvt(dec_w1f, dec_w1, nF);  cvt(dec_w2f, dec_w2, nF);
    cvt(out_Wf, out_W, nO);

    auto gemm = [&](const u16* A, int lda, long sAb, long sAh,
                    const u16* Bp, int ldb, long sBb, long sBh,
                    float* Cf, u16* Cb, int csm, int csn, long sCb, long sCh,
                    const float* bias, const float* res, int ldres,
                    float alpha, int relu, int Z2,
                    int M, int N, int K, int Z)
    {
        dim3 g((unsigned)(N >> 6), (unsigned)(M >> 6), (unsigned)Z);
        gemm_bt<<<g, 256, 0, stream>>>(A, lda, sAb, sAh, Bp, ldb, sBb, sBh,
                                       Cf, Cb, csm, csn, sCb, sCh,
                                       bias, res, ldres, alpha, relu, Z2, K);
    };

    // ---------------- Encoder ----------------
    embed_pe<<<4096, 256, 0, stream>>>(src, src_embed, x);
    for (int l = 0; l < NLay; l++) {
        size_t wo = (size_t)l * Dm * Dm;
        ln_rows<<<NTOK, 64, 0, stream>>>(x, enc_ln1g + l * Dm, enc_ln1b + l * Dm, nrm);
        gemm(nrm, 512, 0, 0, encW[0] + wo, 512, 0, 0, nullptr, qb, 512, 1, 0, 0,
             nullptr, nullptr, 0, 1.f, 0, 1, 2048, 512, 512, 1);
        gemm(nrm, 512, 0, 0, encW[1] + wo, 512, 0, 0, nullptr, kb, 512, 1, 0, 0,
             nullptr, nullptr, 0, 1.f, 0, 1, 2048, 512, 512, 1);
        gemm(nrm, 512, S2, 0, encW[2] + wo, 512, 0, 0, nullptr, vt, 1, 512, S2, 0,
             nullptr, nullptr, 0, 1.f, 0, 1, 512, 512, 512, 4);                 // V^T per batch
        gemm(qb, 512, S2, 64, kb, 512, S2, 64, scor, nullptr, 512, 1, HS2, S2,
             nullptr, nullptr, 0, 0.125f, 0, Hh, 512, 512, 64, 32);             // Q K^T / 8
        softmax_rows<<<dim3(512, Hh, Bb), 64, 0, stream>>>(scor, pmat, src, 0);
        gemm(pmat, 512, HS2, S2, vt, 512, S2, 64L * 512, nullptr, attc, 512, 1, S2, 64,
             nullptr, nullptr, 0, 1.f, 0, Hh, 512, 64, 512, 32);                // P V
        gemm(attc, 512, 0, 0, encW[3] + wo, 512, 0, 0, x, nullptr, 512, 1, 0, 0,
             nullptr, x, 512, 1.f, 0, 1, 2048, 512, 512, 1);                    // O proj + residual
        ln_rows<<<NTOK, 64, 0, stream>>>(x, enc_ln2g + l * Dm, enc_ln2b + l * Dm, nrm);
        gemm(nrm, 512, 0, 0, enc_w1 + (size_t)l * DFFm * Dm, 512, 0, 0, nullptr, h1,
             DFFm, 1, 0, 0, enc_b1 + l * DFFm, nullptr, 0, 1.f, 1, 1, 2048, DFFm, 512, 1);
        gemm(h1, DFFm, 0, 0, enc_w2 + (size_t)l * Dm * DFFm, DFFm, 0, 0, x, nullptr,
             512, 1, 0, 0, enc_b2 + l * Dm, x, 512, 1.f, 0, 1, 2048, 512, DFFm, 1);
    }
    ln_rows<<<NTOK, 64, 0, stream>>>(x, enc_lnfg, enc_lnfb, memn);

    // ---------------- Decoder ----------------
    embed_pe<<<4096, 256, 0, stream>>>(tgt, tgt_embed, y);
    for (int l = 0; l < NLay; l++) {
        size_t wo = (size_t)l * Dm * Dm;
        // self-attention (causal + tgt pad mask)
        ln_rows<<<NTOK, 64, 0, stream>>>(y, dec_ln1g + l * Dm, dec_ln1b + l * Dm, nrm);
        gemm(nrm, 512, 0, 0, decW[0] + wo, 512, 0, 0, nullptr, qb, 512, 1, 0, 0,
             nullptr, nullptr, 0, 1.f, 0, 1, 2048, 512, 512, 1);
        gemm(nrm, 512, 0, 0, decW[1] + wo, 512, 0, 0, nullptr, kb, 512, 1, 0, 0,
             nullptr, nullptr, 0, 1.f, 0, 1, 2048, 512, 512, 1);
        gemm(nrm, 512, S2, 0, decW[2] + wo, 512, 0, 0, nullptr, vt, 1, 512, S2, 0,
             nullptr, nullptr, 0, 1.f, 0, 1, 512, 512, 512, 4);
        gemm(qb, 512, S2, 64, kb, 512, S2, 64, scor, nullptr, 512, 1, HS2, S2,
             nullptr, nullptr, 0, 0.125f, 0, Hh, 512, 512, 64, 32);
        softmax_rows<<<dim3(512, Hh, Bb), 64, 0, stream>>>(scor, pmat, tgt, 1);
        gemm(pmat, 512, HS2, S2, vt, 512, S2, 64L * 512, nullptr, attc, 512, 1, S2, 64,
             nullptr, nullptr, 0, 1.f, 0, Hh, 512, 64, 512, 32);
        gemm(attc, 512, 0, 0, decW[3] + wo, 512, 0, 0, y, nullptr, 512, 1, 0, 0,
             nullptr, y, 512, 1.f, 0, 1, 2048, 512, 512, 1);
        // cross-attention (src pad mask), K/V from encoder memory
        ln_rows<<<NTOK, 64, 0, stream>>>(y, dec_ln2g + l * Dm, dec_ln2b + l * Dm, nrm);
        gemm(nrm, 512, 0, 0, decW[4] + wo, 512, 0, 0, nullptr, qb, 512, 1, 0, 0,
             nullptr, nullptr, 0, 1.f, 0, 1, 2048, 512, 512, 1);
        gemm(memn, 512, 0, 0, decW[5] + wo, 512, 0, 0, nullptr, kb, 512, 1, 0, 0,
             nullptr, nullptr, 0, 1.f, 0, 1, 2048, 512, 512, 1);
        gemm(memn, 512, S2, 0, decW[6] + wo, 512, 0, 0, nullptr, vt, 1, 512, S2, 0,
             nullptr, nullptr, 0, 1.f, 0, 1, 512, 512, 512, 4);
        gemm(qb, 512, S2, 64, kb, 512, S2, 64, scor, nullptr, 512, 1, HS2, S2,
             nullptr, nullptr, 0, 0.125f, 0, Hh, 512, 512, 64, 32);
        softmax_rows<<<dim3(512, Hh, Bb), 64, 0, stream>>>(scor, pmat, src, 0);
        gemm(pmat, 512, HS2, S2, vt, 512, S2, 64L * 512, nullptr, attc, 512, 1, S2, 64,
             nullptr, nullptr, 0, 1.f, 0, Hh, 512, 64, 512, 32);
        gemm(attc, 512, 0, 0, decW[7] + wo, 512, 0, 0, y, nullptr, 512, 1, 0, 0,
             nullptr, y, 512, 1.f, 0, 1, 2048, 512, 512, 1);
        // FFN
        ln_rows<<<NTOK, 64, 0, stream>>>(y, dec_ln3g + l * Dm, dec_ln3b + l * Dm, nrm);
        gemm(nrm, 512, 0, 0, dec_w1 + (size_t)l * DFFm * Dm, 512, 0, 0, nullptr, h1,
             DFFm, 1, 0, 0, dec_b1 + l * DFFm, nullptr, 0, 1.f, 1, 1, 2048, DFFm, 512, 1);
        gemm(h1, DFFm, 0, 0, dec_w2 + (size_t)l * Dm * DFFm, DFFm, 0, 0, y, nullptr,
             512, 1, 0, 0, dec_b2 + l * Dm, y, 512, 1.f, 0, 1, 2048, 512, DFFm, 1);
    }
    ln_rows<<<NTOK, 64, 0, stream>>>(y, dec_lnfg, dec_lnfb, nrm);

    // final projection to vocab: [2048, 32000] f32 out
    gemm(nrm, 512, 0, 0, out_W, 512, 0, 0, (float*)d_out, nullptr, 32000, 1, 0, 0,
         out_b, nullptr, 0, 1.f, 0, 1, 2048, 32000, 512, 1);
}

// Round 3
// 1969.209 us; speedup vs baseline: 1.3193x; 1.3193x over previous
//
#include <hip/hip_runtime.h>
#include <hip/hip_bf16.h>
#include <math.h>

// ---------------- problem constants ----------------
#define Dm    512
#define Hh    8
#define NLay  6
#define DFFm  2048
#define Bb    4
#define NTOK  2048          // B * S
#define PADID 1
#define LNEPS 1e-5f
#define S2W   262144        // 512*512 elements (one [512][512] plane)

typedef __attribute__((ext_vector_type(8))) short short8;   // 8 x bf16 (4 VGPRs)
typedef __attribute__((ext_vector_type(4))) float f32x4;
typedef unsigned short u16;

__device__ __forceinline__ u16 f2bf(float f) {
    union { float f; unsigned int i; } x; x.f = f;
    unsigned int r = x.i + 0x7fffu + ((x.i >> 16) & 1u);   // RNE
    return (u16)(r >> 16);
}

// async global->LDS, 16B per lane (dest = wave-uniform base + lane*16)
typedef const __attribute__((address_space(1))) void* as1cv;
typedef __attribute__((address_space(3))) void* as3v;
__device__ __forceinline__ void gl_lds16(const u16* g, u16* l) {
    __builtin_amdgcn_global_load_lds((as1cv)g, (as3v)l, 16, 0, 0);
}

// f32 -> bf16 elementwise (n4 = n/4 float4s), grid-stride
__global__ __launch_bounds__(256) void cvt_bf16(
    const float* __restrict__ in, u16* __restrict__ out, long n4)
{
    long i = (long)blockIdx.x * 256 + threadIdx.x;
    long stride = (long)gridDim.x * 256;
    for (; i < n4; i += stride) {
        float4 v = ((const float4*)in)[i];
        ushort4 o;
        o.x = f2bf(v.x); o.y = f2bf(v.y); o.z = f2bf(v.z); o.w = f2bf(v.w);
        ((ushort4*)out)[i] = o;
    }
}

// pack up to 3 per-layer [NL][512][512] f32 tensors into [NL][nparts][512][512] bf16
__global__ __launch_bounds__(256) void pack_cvt(
    const float* __restrict__ W0, const float* __restrict__ W1,
    const float* __restrict__ W2, int nparts, u16* __restrict__ out, long n4)
{
    long i = (long)blockIdx.x * 256 + threadIdx.x;
    long stride = (long)gridDim.x * 256;
    for (; i < n4; i += stride) {
        int zp  = (int)(i >> 16);            // 65536 float4 per [512][512] part
        int rem = (int)(i & 65535);
        int lyr = zp / nparts, p = zp - lyr * nparts;
        const float* W = (p == 0) ? W0 : (p == 1) ? W1 : W2;
        float4 v = ((const float4*)W)[(long)lyr * 65536 + rem];
        ushort4 o;
        o.x = f2bf(v.x); o.y = f2bf(v.y); o.z = f2bf(v.z); o.w = f2bf(v.w);
        ((ushort4*)out)[i] = o;
    }
}

// ---------------------------------------------------------------------------
// gemm_bt: C[m,n] = sum_k A[m,k]*B[n,k] (+bias[n]) (+res[m,n])
// 64x64 tile, 4 waves, BK=32, global_load_lds staging with XOR-swizzled source.
// Epilogue: nl >= vth -> write transposed V layout vt[b][nl-vth][s] (b=ml>>9, s=ml&511)
//           else      -> C[ml*csm + nl + koff] (f32 Cf and/or bf16 Cb)
// ---------------------------------------------------------------------------
__global__ __launch_bounds__(256) void gemm_bt(
    const u16* __restrict__ A, int lda,
    const u16* __restrict__ B, int ldb,
    float* Cf, u16* Cb, int csm,
    const float* __restrict__ bias,
    const float* res, int ldres,
    int K, int vth, int koff, u16* vtp)
{
    __shared__ u16 As[64 * 32];
    __shared__ u16 Bs[64 * 32];
    const int t = threadIdx.x, lane = t & 63, wave = t >> 6;
    const int m0 = blockIdx.y << 6, n0 = blockIdx.x << 6;
    const int wr = (wave >> 1) << 5, wc = (wave & 1) << 5;
    const int fr = lane & 15, fq = lane >> 4;
    const int srow = t >> 2;
    const int sch  = (t & 3) ^ (srow & 3);       // source chunk pre-swizzle
    const u16* Ag = A + (long)(m0 + srow) * lda + (sch << 3);
    const u16* Bg = B + (long)(n0 + srow) * ldb + (sch << 3);

    f32x4 acc[2][2];
    #pragma unroll
    for (int i = 0; i < 2; i++)
        #pragma unroll
        for (int j = 0; j < 2; j++) acc[i][j] = (f32x4){0.f, 0.f, 0.f, 0.f};

    for (int k0 = 0; k0 < K; k0 += 32) {
        gl_lds16(Ag + k0, &As[t << 3]);
        gl_lds16(Bg + k0, &Bs[t << 3]);
        __syncthreads();
        const int r0 = wr + fr, r1 = wr + 16 + fr;
        const int c0 = wc + fr, c1 = wc + 16 + fr;
        short8 af0 = *(const short8*)&As[(r0 << 5) + ((fq ^ (r0 & 3)) << 3)];
        short8 af1 = *(const short8*)&As[(r1 << 5) + ((fq ^ (r1 & 3)) << 3)];
        short8 bf0 = *(const short8*)&Bs[(c0 << 5) + ((fq ^ (c0 & 3)) << 3)];
        short8 bf1 = *(const short8*)&Bs[(c1 << 5) + ((fq ^ (c1 & 3)) << 3)];
        acc[0][0] = __builtin_amdgcn_mfma_f32_16x16x32_bf16(af0, bf0, acc[0][0], 0, 0, 0);
        acc[0][1] = __builtin_amdgcn_mfma_f32_16x16x32_bf16(af0, bf1, acc[0][1], 0, 0, 0);
        acc[1][0] = __builtin_amdgcn_mfma_f32_16x16x32_bf16(af1, bf0, acc[1][0], 0, 0, 0);
        acc[1][1] = __builtin_amdgcn_mfma_f32_16x16x32_bf16(af1, bf1, acc[1][1], 0, 0, 0);
        __syncthreads();
    }

    #pragma unroll
    for (int i = 0; i < 2; i++) {
        #pragma unroll
        for (int j = 0; j < 2; j++) {
            const int nl  = n0 + wc + (j << 4) + fr;
            const int mlb = m0 + wr + (i << 4) + (fq << 2);
            const float bsv = bias ? bias[nl] : 0.f;
            #pragma unroll
            for (int r = 0; r < 4; r++) {
                const int ml = mlb + r;
                float v = acc[i][j][r] + bsv;
                if (nl >= vth) {
                    vtp[(long)(ml >> 9) * S2W + (long)(nl - vth) * 512 + (ml & 511)] = f2bf(v);
                } else {
                    long ci = (long)ml * csm + nl + koff;
                    if (res) v += res[(long)ml * ldres + nl];
                    if (Cf) Cf[ci] = v;
                    if (Cb) Cb[ci] = f2bf(v);
                }
            }
        }
    }
}

// ---------------------------------------------------------------------------
// gemm_big: 128x128 tile (m97 structure), 4 waves each 64x64, BK=32.
// ---------------------------------------------------------------------------
__global__ __launch_bounds__(256) void gemm_big(
    const u16* __restrict__ A, int lda,
    const u16* __restrict__ B, int ldb,
    float* Cf, u16* Cb, int ldc,
    const float* __restrict__ bias, int relu, int K)
{
    __shared__ u16 As[128 * 32];
    __shared__ u16 Bs[128 * 32];
    const int t = threadIdx.x, lane = t & 63, wave = t >> 6;
    const int m0 = blockIdx.y << 7, n0 = blockIdx.x << 7;
    const int wr = (wave >> 1) << 6, wc = (wave & 1) << 6;
    const int fr = lane & 15, fq = lane >> 4;
    const int srow = t >> 2;
    const int sch  = (t & 3) ^ (srow & 3);
    const u16* Ag0 = A + (long)(m0 + srow) * lda + (sch << 3);
    const u16* Ag1 = A + (long)(m0 + 64 + srow) * lda + (sch << 3);
    const u16* Bg0 = B + (long)(n0 + srow) * ldb + (sch << 3);
    const u16* Bg1 = B + (long)(n0 + 64 + srow) * ldb + (sch << 3);

    f32x4 acc[4][4];
    #pragma unroll
    for (int i = 0; i < 4; i++)
        #pragma unroll
        for (int j = 0; j < 4; j++) acc[i][j] = (f32x4){0.f, 0.f, 0.f, 0.f};

    for (int k0 = 0; k0 < K; k0 += 32) {
        gl_lds16(Ag0 + k0, &As[t << 3]);
        gl_lds16(Ag1 + k0, &As[2048 + (t << 3)]);
        gl_lds16(Bg0 + k0, &Bs[t << 3]);
        gl_lds16(Bg1 + k0, &Bs[2048 + (t << 3)]);
        __syncthreads();
        short8 af[4], bf[4];
        #pragma unroll
        for (int i = 0; i < 4; i++) {
            const int r = wr + (i << 4) + fr;
            af[i] = *(const short8*)&As[(r << 5) + ((fq ^ (r & 3)) << 3)];
        }
        #pragma unroll
        for (int j = 0; j < 4; j++) {
            const int c = wc + (j << 4) + fr;
            bf[j] = *(const short8*)&Bs[(c << 5) + ((fq ^ (c & 3)) << 3)];
        }
        #pragma unroll
        for (int i = 0; i < 4; i++)
            #pragma unroll
            for (int j = 0; j < 4; j++)
                acc[i][j] = __builtin_amdgcn_mfma_f32_16x16x32_bf16(af[i], bf[j], acc[i][j], 0, 0, 0);
        __syncthreads();
    }

    #pragma unroll
    for (int i = 0; i < 4; i++) {
        #pragma unroll
        for (int j = 0; j < 4; j++) {
            const int nl  = n0 + wc + (j << 4) + fr;
            const int mlb = m0 + wr + (i << 4) + (fq << 2);
            const float bsv = bias ? bias[nl] : 0.f;
            #pragma unroll
            for (int r = 0; r < 4; r++) {
                float v = acc[i][j][r] + bsv;
                if (relu) v = fmaxf(v, 0.f);
                long ci = (long)(mlb + r) * ldc + nl;
                if (Cf) Cf[ci] = v;
                if (Cb) Cb[ci] = f2bf(v);
            }
        }
    }
}

// ---------------------------------------------------------------------------
// Fused attention: one block per (q-tile 64, head, batch). 4 waves, each owns
// 16 q-rows. Online softmax in C/D layout; P via per-wave LDS; no barriers.
// qkb: [2048][1024] (Q cols 0-511, K cols 512-1023); vt: [B][512 d][512 s].
// ---------------------------------------------------------------------------
__global__ __launch_bounds__(256) void attn_fused(
    const u16* __restrict__ qkb, const u16* __restrict__ vt,
    const int* __restrict__ ids, u16* __restrict__ attc, int causal)
{
    __shared__ short Ps[4][16][72];
    const int t = threadIdx.x, lane = t & 63, w = t >> 6;
    const int fr = lane & 15, fq = lane >> 4;
    const int q0 = blockIdx.x << 6, h = blockIdx.y, b = blockIdx.z;

    const u16* qp = qkb + (long)(b * 512 + q0 + (w << 4) + fr) * 1024 + h * 64 + (fq << 3);
    short8 aq0 = *(const short8*)qp;
    short8 aq1 = *(const short8*)(qp + 32);
    const u16* kbase = qkb + (long)(b * 512) * 1024 + 512 + h * 64 + (fq << 3);
    const u16* vbase = vt + (long)b * S2W + (long)(h * 64) * 512 + (fq << 3);

    float m[4], l[4]; f32x4 oc[4];
    #pragma unroll
    for (int r = 0; r < 4; r++) { m[r] = -INFINITY; l[r] = 0.f; oc[r] = (f32x4){0.f,0.f,0.f,0.f}; }

    for (int kt = 0; kt < 8; kt++) {
        const int s0 = kt << 6;
        if (causal && s0 > q0 + 63) break;       // fully-masked tail tiles
        f32x4 sc[4];
        #pragma unroll
        for (int j = 0; j < 4; j++) sc[j] = (f32x4){0.f,0.f,0.f,0.f};
        #pragma unroll
        for (int j = 0; j < 4; j++) {
            const u16* kp = kbase + (long)(s0 + (j << 4) + fr) * 1024;
            short8 bk0 = *(const short8*)kp;
            short8 bk1 = *(const short8*)(kp + 32);
            sc[j] = __builtin_amdgcn_mfma_f32_16x16x32_bf16(aq0, bk0, sc[j], 0, 0, 0);
            sc[j] = __builtin_amdgcn_mfma_f32_16x16x32_bf16(aq1, bk1, sc[j], 0, 0, 0);
        }
        int scol[4], pad[4];
        #pragma unroll
        for (int j = 0; j < 4; j++) {
            scol[j] = s0 + (j << 4) + fr;
            pad[j]  = (ids[b * 512 + scol[j]] == PADID);
        }
        #pragma unroll
        for (int r = 0; r < 4; r++) {
            const int qa = q0 + (w << 4) + (fq << 2) + r;
            float mx = -INFINITY;
            #pragma unroll
            for (int j = 0; j < 4; j++) {
                bool msk = pad[j] || (causal && scol[j] > qa);
                float sv = msk ? -INFINITY : sc[j][r] * 0.125f;
                sc[j][r] = sv;
                mx = fmaxf(mx, sv);
            }
            mx = fmaxf(mx, __shfl_xor(mx, 1)); mx = fmaxf(mx, __shfl_xor(mx, 2));
            mx = fmaxf(mx, __shfl_xor(mx, 4)); mx = fmaxf(mx, __shfl_xor(mx, 8));
            float mnew  = fmaxf(m[r], mx);
            float scale = (mnew == -INFINITY) ? 1.f : __expf(m[r] - mnew);
            float ps = 0.f;
            #pragma unroll
            for (int j = 0; j < 4; j++) {
                float p = (sc[j][r] == -INFINITY) ? 0.f : __expf(sc[j][r] - mnew);
                sc[j][r] = p; ps += p;
            }
            ps += __shfl_xor(ps, 1); ps += __shfl_xor(ps, 2);
            ps += __shfl_xor(ps, 4); ps += __shfl_xor(ps, 8);
            l[r] = l[r] * scale + ps;
            m[r] = mnew;
            #pragma unroll
            for (int j2 = 0; j2 < 4; j2++) oc[j2][r] *= scale;
        }
        #pragma unroll
        for (int r = 0; r < 4; r++)
            #pragma unroll
            for (int j = 0; j < 4; j++)
                Ps[w][(fq << 2) + r][(j << 4) + fr] = (short)f2bf(sc[j][r]);
        #pragma unroll
        for (int kc = 0; kc < 2; kc++) {
            short8 pa = *(const short8*)&Ps[w][fr][(kc << 5) + (fq << 3)];
            #pragma unroll
            for (int j2 = 0; j2 < 4; j2++) {
                short8 bv = *(const short8*)(vbase + (long)((j2 << 4) + fr) * 512 + s0 + (kc << 5));
                oc[j2] = __builtin_amdgcn_mfma_f32_16x16x32_bf16(pa, bv, oc[j2], 0, 0, 0);
            }
        }
    }
    float inv[4];
    #pragma unroll
    for (int r = 0; r < 4; r++) inv[r] = (l[r] > 0.f) ? 1.f / l[r] : 0.f;
    #pragma unroll
    for (int j2 = 0; j2 < 4; j2++)
        #pragma unroll
        for (int r = 0; r < 4; r++)
            attc[(long)(b * 512 + q0 + (w << 4) + (fq << 2) + r) * 512 + h * 64 + (j2 << 4) + fr]
                = f2bf(oc[j2][r] * inv[r]);
}

// LayerNorm over D=512: 4 rows/block (wave per row). f32 in -> bf16 out.
__global__ __launch_bounds__(256) void ln_rows(
    const float* __restrict__ x, const float* __restrict__ g,
    const float* __restrict__ b, u16* __restrict__ out)
{
    int row  = blockIdx.x * 4 + (threadIdx.x >> 6);
    int lane = threadIdx.x & 63;
    const float* xr = x + (long)row * Dm;
    float v[8]; float s = 0.f;
    #pragma unroll
    for (int i = 0; i < 8; i++) { v[i] = xr[lane + (i << 6)]; s += v[i]; }
    #pragma unroll
    for (int o = 32; o > 0; o >>= 1) s += __shfl_xor(s, o);
    float mean = s * (1.f / 512.f);
    float q = 0.f;
    #pragma unroll
    for (int i = 0; i < 8; i++) { float d = v[i] - mean; q += d * d; }
    #pragma unroll
    for (int o = 32; o > 0; o >>= 1) q += __shfl_xor(q, o);
    float rinv = rsqrtf(q * (1.f / 512.f) + LNEPS);
    u16* orow = out + (long)row * Dm;
    #pragma unroll
    for (int i = 0; i < 8; i++) {
        int c = lane + (i << 6);
        orow[c] = f2bf((v[i] - mean) * rinv * g[c] + b[c]);
    }
}

// x[b,s,:] = embed[id]*sqrt(D) + PE(s,:)   (f32 in/out)
__global__ __launch_bounds__(256) void embed_pe(
    const int* __restrict__ ids, const float* __restrict__ emb,
    float* __restrict__ out)
{
    int idx = blockIdx.x * 256 + threadIdx.x;   // NTOK*512 = 2^20
    int d   = idx & 511;
    int tok = idx >> 9;
    int s   = tok & 511;
    int id  = ids[tok];
    float val = emb[(long)id * Dm + d] * 22.62741699796952f;     // sqrt(512)
    int i2 = d >> 1;
    float dv  = expf((float)(i2 << 1) * (-9.210340371976184f / 512.f));
    float ang = (float)s * dv;
    val += (d & 1) ? cosf(ang) : sinf(ang);
    out[idx] = val;
}

// ---------------------------------------------------------------------------
extern "C" void kernel_launch(void* const* d_in, const int* in_sizes, int n_in,
                              void* d_out, int out_size, void* d_ws, size_t ws_size,
                              hipStream_t stream)
{
    (void)in_sizes; (void)n_in; (void)out_size; (void)ws_size;
    const int*   src       = (const int*)d_in[0];
    const int*   tgt       = (const int*)d_in[1];
    const float* src_embed = (const float*)d_in[2];
    const float* tgt_embed = (const float*)d_in[3];
    const float* enc_Wq = (const float*)d_in[4];
    const float* enc_Wk = (const float*)d_in[5];
    const float* enc_Wv = (const float*)d_in[6];
    const float* enc_Wo = (const float*)d_in[7];
    const float* enc_w1f = (const float*)d_in[8];
    const float* enc_b1  = (const float*)d_in[9];
    const float* enc_w2f = (const float*)d_in[10];
    const float* enc_b2  = (const float*)d_in[11];
    const float* enc_ln1g = (const float*)d_in[12];
    const float* enc_ln1b = (const float*)d_in[13];
    const float* enc_ln2g = (const float*)d_in[14];
    const float* enc_ln2b = (const float*)d_in[15];
    const float* enc_lnfg = (const float*)d_in[16];
    const float* enc_lnfb = (const float*)d_in[17];
    const float* dec_sWq = (const float*)d_in[18];
    const float* dec_sWk = (const float*)d_in[19];
    const float* dec_sWv = (const float*)d_in[20];
    const float* dec_sWo = (const float*)d_in[21];
    const float* dec_cWq = (const float*)d_in[22];
    const float* dec_cWk = (const float*)d_in[23];
    const float* dec_cWv = (const float*)d_in[24];
    const float* dec_cWo = (const float*)d_in[25];
    const float* dec_w1f = (const float*)d_in[26];
    const float* dec_b1  = (const float*)d_in[27];
    const float* dec_w2f = (const float*)d_in[28];
    const float* dec_b2  = (const float*)d_in[29];
    const float* dec_ln1g = (const float*)d_in[30];
    const float* dec_ln1b = (const float*)d_in[31];
    const float* dec_ln2g = (const float*)d_in[32];
    const float* dec_ln2b = (const float*)d_in[33];
    const float* dec_ln3g = (const float*)d_in[34];
    const float* dec_ln3b = (const float*)d_in[35];
    const float* dec_lnfg = (const float*)d_in[36];
    const float* dec_lnfb = (const float*)d_in[37];
    const float* out_Wf = (const float*)d_in[38];
    const float* out_b  = (const float*)d_in[39];

    char* wp = (char*)d_ws;
    auto carve = [&](size_t nbytes) {
        void* p = (void*)wp; wp += (nbytes + 255) & ~(size_t)255; return p;
    };

    const long nW = (long)NLay * S2W;            // per-matrix elements over layers
    const long nF = (long)NLay * DFFm * Dm;
    const long nO = 32000L * Dm;
    u16* qkvW_e = (u16*)carve((size_t)nW * 3 * 2);   // [l][q|k|v][512][512]
    u16* qkvW_s = (u16*)carve((size_t)nW * 3 * 2);
    u16* kvW_c  = (u16*)carve((size_t)nW * 2 * 2);   // [l][k|v][512][512]
    u16* WoE  = (u16*)carve((size_t)nW * 2);
    u16* sWo  = (u16*)carve((size_t)nW * 2);
    u16* cWq  = (u16*)carve((size_t)nW * 2);
    u16* cWo  = (u16*)carve((size_t)nW * 2);
    u16* w1E  = (u16*)carve((size_t)nF * 2);
    u16* w2E  = (u16*)carve((size_t)nF * 2);
    u16* w1D  = (u16*)carve((size_t)nF * 2);
    u16* w2D  = (u16*)carve((size_t)nF * 2);
    u16* outW = (u16*)carve((size_t)nO * 2);

    float* x  = (float*)carve((size_t)NTOK * Dm * 4);
    float* y  = (float*)carve((size_t)NTOK * Dm * 4);
    u16* nrm  = (u16*)carve((size_t)NTOK * Dm * 2);
    u16* qkb  = (u16*)carve((size_t)NTOK * 1024 * 2);
    u16* vt   = (u16*)carve((size_t)Bb * Dm * 512 * 2);
    u16* attc = (u16*)carve((size_t)NTOK * Dm * 2);
    u16* h1   = (u16*)carve((size_t)NTOK * DFFm * 2);
    u16* memn = (u16*)carve((size_t)NTOK * Dm * 2);

    auto cvt = [&](const float* in, u16* out, long n) {
        long n4 = n >> 2;
        int blocks = (int)((n4 + 255) / 256); if (blocks > 2048) blocks = 2048;
        cvt_bf16<<<blocks, 256, 0, stream>>>(in, out, n4);
    };
    auto pack = [&](const float* W0, const float* W1, const float* W2, int np, u16* out) {
        long n4 = ((long)NLay * np * S2W) >> 2;
        int blocks = (int)((n4 + 255) / 256); if (blocks > 2048) blocks = 2048;
        pack_cvt<<<blocks, 256, 0, stream>>>(W0, W1, W2, np, out, n4);
    };
    pack(enc_Wq, enc_Wk, enc_Wv, 3, qkvW_e);
    pack(dec_sWq, dec_sWk, dec_sWv, 3, qkvW_s);
    pack(dec_cWk, dec_cWv, nullptr, 2, kvW_c);
    cvt(enc_Wo, WoE, nW);  cvt(dec_sWo, sWo, nW);
    cvt(dec_cWq, cWq, nW); cvt(dec_cWo, cWo, nW);
    cvt(enc_w1f, w1E, nF); cvt(enc_w2f, w2E, nF);
    cvt(dec_w1f, w1D, nF); cvt(dec_w2f, w2D, nF);
    cvt(out_Wf, outW, nO);

    const int BIG = 1 << 28;

    // ---------------- Encoder ----------------
    embed_pe<<<4096, 256, 0, stream>>>(src, src_embed, x);
    for (int l = 0; l < NLay; l++) {
        ln_rows<<<512, 256, 0, stream>>>(x, enc_ln1g + l * Dm, enc_ln1b + l * Dm, nrm);
        gemm_bt<<<dim3(24, 32), 256, 0, stream>>>(nrm, 512, qkvW_e + (size_t)l * 3 * S2W, 512,
            nullptr, qkb, 1024, nullptr, nullptr, 0, 512, 1024, 0, vt);
        attn_fused<<<dim3(8, Hh, Bb), 256, 0, stream>>>(qkb, vt, src, attc, 0);
        gemm_bt<<<dim3(8, 32), 256, 0, stream>>>(attc, 512, WoE + (size_t)l * S2W, 512,
            x, nullptr, 512, nullptr, x, 512, 512, BIG, 0, nullptr);
        ln_rows<<<512, 256, 0, stream>>>(x, enc_ln2g + l * Dm, enc_ln2b + l * Dm, nrm);
        gemm_big<<<dim3(16, 16), 256, 0, stream>>>(nrm, 512, w1E + (size_t)l * DFFm * Dm, 512,
            nullptr, h1, DFFm, enc_b1 + l * DFFm, 1, 512);
        gemm_bt<<<dim3(8, 32), 256, 0, stream>>>(h1, DFFm, w2E + (size_t)l * Dm * DFFm, DFFm,
            x, nullptr, 512, enc_b2 + l * Dm, x, 512, 2048, BIG, 0, nullptr);
    }
    ln_rows<<<512, 256, 0, stream>>>(x, enc_lnfg, enc_lnfb, memn);

    // ---------------- Decoder ----------------
    embed_pe<<<4096, 256, 0, stream>>>(tgt, tgt_embed, y);
    for (int l = 0; l < NLay; l++) {
        // self-attention (causal + tgt pad)
        ln_rows<<<512, 256, 0, stream>>>(y, dec_ln1g + l * Dm, dec_ln1b + l * Dm, nrm);
        gemm_bt<<<dim3(24, 32), 256, 0, stream>>>(nrm, 512, qkvW_s + (size_t)l * 3 * S2W, 512,
            nullptr, qkb, 1024, nullptr, nullptr, 0, 512, 1024, 0, vt);
        attn_fused<<<dim3(8, Hh, Bb), 256, 0, stream>>>(qkb, vt, tgt, attc, 1);
        gemm_bt<<<dim3(8, 32), 256, 0, stream>>>(attc, 512, sWo + (size_t)l * S2W, 512,
            y, nullptr, 512, nullptr, y, 512, 512, BIG, 0, nullptr);
        // cross-attention (src pad), K/V from encoder memory
        ln_rows<<<512, 256, 0, stream>>>(y, dec_ln2g + l * Dm, dec_ln2b + l * Dm, nrm);
        gemm_bt<<<dim3(8, 32), 256, 0, stream>>>(nrm, 512, cWq + (size_t)l * S2W, 512,
            nullptr, qkb, 1024, nullptr, nullptr, 0, 512, BIG, 0, nullptr);
        gemm_bt<<<dim3(16, 32), 256, 0, stream>>>(memn, 512, kvW_c + (size_t)l * 2 * S2W, 512,
            nullptr, qkb, 1024, nullptr, nullptr, 0, 512, 512, 512, vt);
        attn_fused<<<dim3(8, Hh, Bb), 256, 0, stream>>>(qkb, vt, src, attc, 0);
        gemm_bt<<<dim3(8, 32), 256, 0, stream>>>(attc, 512, cWo + (size_t)l * S2W, 512,
            y, nullptr, 512, nullptr, y, 512, 512, BIG, 0, nullptr);
        // FFN
        ln_rows<<<512, 256, 0, stream>>>(y, dec_ln3g + l * Dm, dec_ln3b + l * Dm, nrm);
        gemm_big<<<dim3(16, 16), 256, 0, stream>>>(nrm, 512, w1D + (size_t)l * DFFm * Dm, 512,
            nullptr, h1, DFFm, dec_b1 + l * DFFm, 1, 512);
        gemm_bt<<<dim3(8, 32), 256, 0, stream>>>(h1, DFFm, w2D + (size_t)l * Dm * DFFm, DFFm,
            y, nullptr, 512, dec_b2 + l * Dm, y, 512, 2048, BIG, 0, nullptr);
    }
    ln_rows<<<512, 256, 0, stream>>>(y, dec_lnfg, dec_lnfb, nrm);

    // final projection to vocab: [2048][32000] f32 out
    gemm_big<<<dim3(250, 16), 256, 0, stream>>>(nrm, 512, outW, 512,
        (float*)d_out, nullptr, 32000, out_b, 0, 512);
}

// Round 4
// 1919.069 us; speedup vs baseline: 1.3538x; 1.0261x over previous
//
#include <hip/hip_runtime.h>
#include <hip/hip_bf16.h>
#include <math.h>

// ---------------- problem constants ----------------
#define Dm    512
#define Hh    8
#define NLay  6
#define DFFm  2048
#define Bb    4
#define NTOK  2048          // B * S
#define PADID 1
#define LNEPS 1e-5f
#define S2W   262144        // 512*512 elements (one [512][512] plane)

typedef __attribute__((ext_vector_type(8))) short short8;   // 8 x bf16 (4 VGPRs)
typedef __attribute__((ext_vector_type(4))) float f32x4;
typedef unsigned short u16;

__device__ __forceinline__ u16 f2bf(float f) {
    union { float f; unsigned int i; } x; x.f = f;
    unsigned int r = x.i + 0x7fffu + ((x.i >> 16) & 1u);   // RNE
    return (u16)(r >> 16);
}

// async global->LDS, 16B per lane (dest must be linear-in-lane: base+lane*16)
typedef const __attribute__((address_space(1))) void* as1cv;
typedef __attribute__((address_space(3))) void* as3v;
__device__ __forceinline__ void gl_lds16(const u16* g, u16* l) {
    __builtin_amdgcn_global_load_lds((as1cv)g, (as3v)l, 16, 0, 0);
}

// bijective XCD-chunk swizzle (m204): XCD x owns logical wgids [chunk], decode
// with M fastest so consecutive wgids on one XCD share the B panel (L2 reuse).
__device__ __forceinline__ void swz_tile(int& mt, int& nt) {
    const int nwg  = gridDim.x * gridDim.y;
    const int orig = blockIdx.y * gridDim.x + blockIdx.x;   // hw dispatch order
    const int q8 = nwg >> 3, r8 = nwg & 7;
    const int xcd = orig & 7, idx = orig >> 3;
    const int wgid = (xcd < r8 ? xcd * (q8 + 1) : r8 * (q8 + 1) + (xcd - r8) * q8) + idx;
    const int MT = gridDim.y;
    mt = wgid % MT;
    nt = wgid / MT;
}

// ---- one-launch f32->bf16 conversion of all 17 weight tensors ----
struct CvtJobs {
    const float* s[17];
    u16*         d[17];
    long         n4[17];
};
__global__ __launch_bounds__(256) void cvt_many(CvtJobs j) {
    const int job = blockIdx.y;
    const long n4 = j.n4[job];
    const float* in = j.s[job];
    u16* out = j.d[job];
    long i = (long)blockIdx.x * 256 + threadIdx.x;
    const long stride = (long)gridDim.x * 256;
    for (; i < n4; i += stride) {
        float4 v = ((const float4*)in)[i];
        ushort4 o;
        o.x = f2bf(v.x); o.y = f2bf(v.y); o.z = f2bf(v.z); o.w = f2bf(v.w);
        ((ushort4*)out)[i] = o;
    }
}

// ---------------------------------------------------------------------------
// gemm_bt: C[m,n] = sum_k A[m,k]*B[n,k] (+bias[n]) (+res[m,n])
// 64x64 tile, 4 waves, BK=32, 2-phase pipeline (prologue stage, per-step:
// sync -> issue next global_load_lds -> MFMA current). XCD-chunk swizzled grid.
// B selected from 3 part pointers by n0>>9 (512-row parts).
// Epilogue: nl >= vth -> vt[b][nl-vth][s]; else C[ml*csm + nl + koff].
// ---------------------------------------------------------------------------
__global__ __launch_bounds__(256) void gemm_bt(
    const u16* __restrict__ A, int lda,
    const u16* __restrict__ B0, const u16* __restrict__ B1,
    const u16* __restrict__ B2, int ldb,
    float* Cf, u16* Cb, int csm,
    const float* __restrict__ bias,
    const float* res, int ldres,
    int K, int vth, int koff, u16* vtp)
{
    __shared__ u16 As[2][2048];
    __shared__ u16 Bs[2][2048];
    int mt, nt; swz_tile(mt, nt);
    const int m0 = mt << 6, n0 = nt << 6;
    const int t = threadIdx.x, lane = t & 63, wave = t >> 6;
    const int wr = (wave >> 1) << 5, wc = (wave & 1) << 5;
    const int fr = lane & 15, fq = lane >> 4;
    const int srow = t >> 2;
    const int sch  = (t & 3) ^ (srow & 3);       // source chunk pre-swizzle
    const u16* Bsel = (n0 < 512) ? B0 : (n0 < 1024 ? B1 : B2);
    const u16* Ag = A + (long)(m0 + srow) * lda + (sch << 3);
    const u16* Bg = Bsel + (long)((n0 & 511) + srow) * ldb + (sch << 3);

    f32x4 acc[2][2];
    #pragma unroll
    for (int i = 0; i < 2; i++)
        #pragma unroll
        for (int j = 0; j < 2; j++) acc[i][j] = (f32x4){0.f, 0.f, 0.f, 0.f};

    const int nk = K >> 5;
    gl_lds16(Ag, &As[0][t << 3]);
    gl_lds16(Bg, &Bs[0][t << 3]);
    for (int ki = 0; ki < nk; ki++) {
        const int cur = ki & 1;
        __syncthreads();                          // buf[cur] ready
        if (ki + 1 < nk) {                        // overlap next loads w/ MFMA
            gl_lds16(Ag + ((ki + 1) << 5), &As[cur ^ 1][t << 3]);
            gl_lds16(Bg + ((ki + 1) << 5), &Bs[cur ^ 1][t << 3]);
        }
        const int r0 = wr + fr, r1 = wr + 16 + fr;
        const int c0 = wc + fr, c1 = wc + 16 + fr;
        short8 af0 = *(const short8*)&As[cur][(r0 << 5) + ((fq ^ (r0 & 3)) << 3)];
        short8 af1 = *(const short8*)&As[cur][(r1 << 5) + ((fq ^ (r1 & 3)) << 3)];
        short8 bf0 = *(const short8*)&Bs[cur][(c0 << 5) + ((fq ^ (c0 & 3)) << 3)];
        short8 bf1 = *(const short8*)&Bs[cur][(c1 << 5) + ((fq ^ (c1 & 3)) << 3)];
        acc[0][0] = __builtin_amdgcn_mfma_f32_16x16x32_bf16(af0, bf0, acc[0][0], 0, 0, 0);
        acc[0][1] = __builtin_amdgcn_mfma_f32_16x16x32_bf16(af0, bf1, acc[0][1], 0, 0, 0);
        acc[1][0] = __builtin_amdgcn_mfma_f32_16x16x32_bf16(af1, bf0, acc[1][0], 0, 0, 0);
        acc[1][1] = __builtin_amdgcn_mfma_f32_16x16x32_bf16(af1, bf1, acc[1][1], 0, 0, 0);
        __syncthreads();                          // safe to overwrite buf[cur]
    }

    #pragma unroll
    for (int i = 0; i < 2; i++) {
        #pragma unroll
        for (int j = 0; j < 2; j++) {
            const int nl  = n0 + wc + (j << 4) + fr;
            const int mlb = m0 + wr + (i << 4) + (fq << 2);
            const float bsv = bias ? bias[nl] : 0.f;
            #pragma unroll
            for (int r = 0; r < 4; r++) {
                const int ml = mlb + r;
                float v = acc[i][j][r] + bsv;
                if (nl >= vth) {
                    vtp[(long)(ml >> 9) * S2W + (long)(nl - vth) * 512 + (ml & 511)] = f2bf(v);
                } else {
                    long ci = (long)ml * csm + nl + koff;
                    if (res) v += res[(long)ml * ldres + nl];
                    if (Cf) Cf[ci] = v;
                    if (Cb) Cb[ci] = f2bf(v);
                }
            }
        }
    }
}

// ---------------------------------------------------------------------------
// gemm_big: 128x128 tile, 4 waves each 64x64, BK=32, 2-phase pipeline,
// XCD-chunk swizzled grid (B-panel per XCD fits its private L2).
// ---------------------------------------------------------------------------
__global__ __launch_bounds__(256) void gemm_big(
    const u16* __restrict__ A, int lda,
    const u16* __restrict__ B, int ldb,
    float* Cf, u16* Cb, int ldc,
    const float* __restrict__ bias, int relu, int K)
{
    __shared__ u16 As[2][4096];
    __shared__ u16 Bs[2][4096];
    int mt, nt; swz_tile(mt, nt);
    const int m0 = mt << 7, n0 = nt << 7;
    const int t = threadIdx.x, lane = t & 63, wave = t >> 6;
    const int wr = (wave >> 1) << 6, wc = (wave & 1) << 6;
    const int fr = lane & 15, fq = lane >> 4;
    const int srow = t >> 2;
    const int sch  = (t & 3) ^ (srow & 3);
    const u16* Ag0 = A + (long)(m0 + srow) * lda + (sch << 3);
    const u16* Ag1 = A + (long)(m0 + 64 + srow) * lda + (sch << 3);
    const u16* Bg0 = B + (long)(n0 + srow) * ldb + (sch << 3);
    const u16* Bg1 = B + (long)(n0 + 64 + srow) * ldb + (sch << 3);

    f32x4 acc[4][4];
    #pragma unroll
    for (int i = 0; i < 4; i++)
        #pragma unroll
        for (int j = 0; j < 4; j++) acc[i][j] = (f32x4){0.f, 0.f, 0.f, 0.f};

    const int nk = K >> 5;
    gl_lds16(Ag0, &As[0][t << 3]);
    gl_lds16(Ag1, &As[0][2048 + (t << 3)]);
    gl_lds16(Bg0, &Bs[0][t << 3]);
    gl_lds16(Bg1, &Bs[0][2048 + (t << 3)]);
    for (int ki = 0; ki < nk; ki++) {
        const int cur = ki & 1;
        __syncthreads();
        if (ki + 1 < nk) {
            const int ko = (ki + 1) << 5;
            gl_lds16(Ag0 + ko, &As[cur ^ 1][t << 3]);
            gl_lds16(Ag1 + ko, &As[cur ^ 1][2048 + (t << 3)]);
            gl_lds16(Bg0 + ko, &Bs[cur ^ 1][t << 3]);
            gl_lds16(Bg1 + ko, &Bs[cur ^ 1][2048 + (t << 3)]);
        }
        short8 af[4], bf[4];
        #pragma unroll
        for (int i = 0; i < 4; i++) {
            const int r = wr + (i << 4) + fr;
            af[i] = *(const short8*)&As[cur][(r << 5) + ((fq ^ (r & 3)) << 3)];
        }
        #pragma unroll
        for (int j = 0; j < 4; j++) {
            const int c = wc + (j << 4) + fr;
            bf[j] = *(const short8*)&Bs[cur][(c << 5) + ((fq ^ (c & 3)) << 3)];
        }
        #pragma unroll
        for (int i = 0; i < 4; i++)
            #pragma unroll
            for (int j = 0; j < 4; j++)
                acc[i][j] = __builtin_amdgcn_mfma_f32_16x16x32_bf16(af[i], bf[j], acc[i][j], 0, 0, 0);
        __syncthreads();
    }

    #pragma unroll
    for (int i = 0; i < 4; i++) {
        #pragma unroll
        for (int j = 0; j < 4; j++) {
            const int nl  = n0 + wc + (j << 4) + fr;
            const int mlb = m0 + wr + (i << 4) + (fq << 2);
            const float bsv = bias ? bias[nl] : 0.f;
            #pragma unroll
            for (int r = 0; r < 4; r++) {
                float v = acc[i][j][r] + bsv;
                if (relu) v = fmaxf(v, 0.f);
                long ci = (long)(mlb + r) * ldc + nl;
                if (Cf) Cf[ci] = v;
                if (Cb) Cb[ci] = f2bf(v);
            }
        }
    }
}

// ---------------------------------------------------------------------------
// Fused attention: block per (q-tile 64, head, batch), 4 waves x 16 q-rows.
// K/V tiles staged in LDS (shared by all waves), double-buffered, source
// pre-swizzled (c' = c ^ (row&7)) so swizzled ds_reads are conflict-free.
// ---------------------------------------------------------------------------
__global__ __launch_bounds__(256) void attn_fused(
    const u16* __restrict__ qkb, const u16* __restrict__ vt,
    const int* __restrict__ ids, u16* __restrict__ attc, int causal)
{
    __shared__ u16 Ks[2][4096];
    __shared__ u16 Vs[2][4096];
    __shared__ short Ps[4][16][72];
    const int t = threadIdx.x, lane = t & 63, w = t >> 6;
    const int fr = lane & 15, fq = lane >> 4;
    const int q0 = blockIdx.x << 6, h = blockIdx.y, b = blockIdx.z;

    const u16* qp = qkb + (long)(b * 512 + q0 + (w << 4) + fr) * 1024 + h * 64 + (fq << 3);
    short8 aq0 = *(const short8*)qp;
    short8 aq1 = *(const short8*)(qp + 32);

    // staging: 512 16B-chunks per tile; thread t stages chunks t and t+256.
    // logical chunk = row*8 + c ; source column chunk c' = c ^ (row&7).
    const int sr0 = t >> 3,        sc0 = (t & 7) ^ (sr0 & 7);
    const int sr1 = (t + 256) >> 3, sc1 = ((t + 256) & 7) ^ (sr1 & 7);
    const u16* kg0 = qkb + (long)(b * 512 + sr0) * 1024 + 512 + h * 64 + (sc0 << 3);
    const u16* kg1 = qkb + (long)(b * 512 + sr1) * 1024 + 512 + h * 64 + (sc1 << 3);
    const u16* vg0 = vt + (long)b * S2W + (long)(h * 64 + sr0) * 512 + (sc0 << 3);
    const u16* vg1 = vt + (long)b * S2W + (long)(h * 64 + sr1) * 512 + (sc1 << 3);

    // pad mask for all 512 keys (bit kt*4+j), computed once
    unsigned pmask = 0;
    #pragma unroll
    for (int kt = 0; kt < 8; kt++)
        #pragma unroll
        for (int j = 0; j < 4; j++)
            if (ids[b * 512 + (kt << 6) + (j << 4) + fr] == PADID)
                pmask |= 1u << ((kt << 2) + j);

    float m[4], l[4]; f32x4 oc[4];
    #pragma unroll
    for (int r = 0; r < 4; r++) { m[r] = -INFINITY; l[r] = 0.f; oc[r] = (f32x4){0.f,0.f,0.f,0.f}; }

    const int lastkt = causal ? (q0 >> 6) : 7;
    auto stage = [&](int kt, int buf) {
        const long so = (long)(kt << 6);
        gl_lds16(kg0 + so * 1024, &Ks[buf][t << 3]);
        gl_lds16(kg1 + so * 1024, &Ks[buf][(t + 256) << 3]);
        gl_lds16(vg0 + so, &Vs[buf][t << 3]);
        gl_lds16(vg1 + so, &Vs[buf][(t + 256) << 3]);
    };
    stage(0, 0);

    for (int kt = 0; kt <= lastkt; kt++) {
        const int cur = kt & 1;
        __syncthreads();                       // buf[cur] staged
        if (kt < lastkt) stage(kt + 1, cur ^ 1);

        f32x4 sc[4];
        #pragma unroll
        for (int j = 0; j < 4; j++) sc[j] = (f32x4){0.f,0.f,0.f,0.f};
        #pragma unroll
        for (int j = 0; j < 4; j++) {
            const int rr = (j << 4) + fr;
            short8 bk0 = *(const short8*)&Ks[cur][rr * 64 + ((fq ^ (rr & 7)) << 3)];
            short8 bk1 = *(const short8*)&Ks[cur][rr * 64 + (((fq | 4) ^ (rr & 7)) << 3)];
            sc[j] = __builtin_amdgcn_mfma_f32_16x16x32_bf16(aq0, bk0, sc[j], 0, 0, 0);
            sc[j] = __builtin_amdgcn_mfma_f32_16x16x32_bf16(aq1, bk1, sc[j], 0, 0, 0);
        }
        const int s0 = kt << 6;
        #pragma unroll
        for (int r = 0; r < 4; r++) {
            const int qa = q0 + (w << 4) + (fq << 2) + r;
            float mx = -INFINITY;
            #pragma unroll
            for (int j = 0; j < 4; j++) {
                bool msk = ((pmask >> ((kt << 2) + j)) & 1) ||
                           (causal && (s0 + (j << 4) + fr) > qa);
                float sv = msk ? -INFINITY : sc[j][r] * 0.125f;
                sc[j][r] = sv;
                mx = fmaxf(mx, sv);
            }
            mx = fmaxf(mx, __shfl_xor(mx, 1)); mx = fmaxf(mx, __shfl_xor(mx, 2));
            mx = fmaxf(mx, __shfl_xor(mx, 4)); mx = fmaxf(mx, __shfl_xor(mx, 8));
            float mnew  = fmaxf(m[r], mx);
            float scale = (mnew == -INFINITY) ? 1.f : __expf(m[r] - mnew);
            float ps = 0.f;
            #pragma unroll
            for (int j = 0; j < 4; j++) {
                float p = (sc[j][r] == -INFINITY) ? 0.f : __expf(sc[j][r] - mnew);
                sc[j][r] = p; ps += p;
            }
            ps += __shfl_xor(ps, 1); ps += __shfl_xor(ps, 2);
            ps += __shfl_xor(ps, 4); ps += __shfl_xor(ps, 8);
            l[r] = l[r] * scale + ps;
            m[r] = mnew;
            #pragma unroll
            for (int j2 = 0; j2 < 4; j2++) oc[j2][r] *= scale;
        }
        #pragma unroll
        for (int r = 0; r < 4; r++)
            #pragma unroll
            for (int j = 0; j < 4; j++)
                Ps[w][(fq << 2) + r][(j << 4) + fr] = (short)f2bf(sc[j][r]);
        #pragma unroll
        for (int kc = 0; kc < 2; kc++) {
            short8 pa = *(const short8*)&Ps[w][fr][(kc << 5) + (fq << 3)];
            #pragma unroll
            for (int j2 = 0; j2 < 4; j2++) {
                const int rd = (j2 << 4) + fr;
                const int cch = (((kc << 2) | fq) ^ (rd & 7));
                short8 bv = *(const short8*)&Vs[cur][rd * 64 + (cch << 3)];
                oc[j2] = __builtin_amdgcn_mfma_f32_16x16x32_bf16(pa, bv, oc[j2], 0, 0, 0);
            }
        }
        __syncthreads();                       // done reading buf[cur]
    }

    float inv[4];
    #pragma unroll
    for (int r = 0; r < 4; r++) inv[r] = (l[r] > 0.f) ? 1.f / l[r] : 0.f;
    #pragma unroll
    for (int j2 = 0; j2 < 4; j2++)
        #pragma unroll
        for (int r = 0; r < 4; r++)
            attc[(long)(b * 512 + q0 + (w << 4) + (fq << 2) + r) * 512 + h * 64 + (j2 << 4) + fr]
                = f2bf(oc[j2][r] * inv[r]);
}

// LayerNorm over D=512: 4 rows/block (wave per row). f32 in -> bf16 out.
__global__ __launch_bounds__(256) void ln_rows(
    const float* __restrict__ x, const float* __restrict__ g,
    const float* __restrict__ b, u16* __restrict__ out)
{
    int row  = blockIdx.x * 4 + (threadIdx.x >> 6);
    int lane = threadIdx.x & 63;
    const float* xr = x + (long)row * Dm;
    float v[8]; float s = 0.f;
    #pragma unroll
    for (int i = 0; i < 8; i++) { v[i] = xr[lane + (i << 6)]; s += v[i]; }
    #pragma unroll
    for (int o = 32; o > 0; o >>= 1) s += __shfl_xor(s, o);
    float mean = s * (1.f / 512.f);
    float q = 0.f;
    #pragma unroll
    for (int i = 0; i < 8; i++) { float d = v[i] - mean; q += d * d; }
    #pragma unroll
    for (int o = 32; o > 0; o >>= 1) q += __shfl_xor(q, o);
    float rinv = rsqrtf(q * (1.f / 512.f) + LNEPS);
    u16* orow = out + (long)row * Dm;
    #pragma unroll
    for (int i = 0; i < 8; i++) {
        int c = lane + (i << 6);
        orow[c] = f2bf((v[i] - mean) * rinv * g[c] + b[c]);
    }
}

// x[b,s,:] = embed[id]*sqrt(D) + PE(s,:)   (f32 in/out)
__global__ __launch_bounds__(256) void embed_pe(
    const int* __restrict__ ids, const float* __restrict__ emb,
    float* __restrict__ out)
{
    int idx = blockIdx.x * 256 + threadIdx.x;   // NTOK*512 = 2^20
    int d   = idx & 511;
    int tok = idx >> 9;
    int s   = tok & 511;
    int id  = ids[tok];
    float val = emb[(long)id * Dm + d] * 22.62741699796952f;     // sqrt(512)
    int i2 = d >> 1;
    float dv  = expf((float)(i2 << 1) * (-9.210340371976184f / 512.f));
    float ang = (float)s * dv;
    val += (d & 1) ? cosf(ang) : sinf(ang);
    out[idx] = val;
}

// ---------------------------------------------------------------------------
extern "C" void kernel_launch(void* const* d_in, const int* in_sizes, int n_in,
                              void* d_out, int out_size, void* d_ws, size_t ws_size,
                              hipStream_t stream)
{
    (void)in_sizes; (void)n_in; (void)out_size; (void)ws_size;
    const int*   src       = (const int*)d_in[0];
    const int*   tgt       = (const int*)d_in[1];
    const float* src_embed = (const float*)d_in[2];
    const float* tgt_embed = (const float*)d_in[3];
    const float* enc_b1  = (const float*)d_in[9];
    const float* enc_b2  = (const float*)d_in[11];
    const float* enc_ln1g = (const float*)d_in[12];
    const float* enc_ln1b = (const float*)d_in[13];
    const float* enc_ln2g = (const float*)d_in[14];
    const float* enc_ln2b = (const float*)d_in[15];
    const float* enc_lnfg = (const float*)d_in[16];
    const float* enc_lnfb = (const float*)d_in[17];
    const float* dec_b1  = (const float*)d_in[27];
    const float* dec_b2  = (const float*)d_in[29];
    const float* dec_ln1g = (const float*)d_in[30];
    const float* dec_ln1b = (const float*)d_in[31];
    const float* dec_ln2g = (const float*)d_in[32];
    const float* dec_ln2b = (const float*)d_in[33];
    const float* dec_ln3g = (const float*)d_in[34];
    const float* dec_ln3b = (const float*)d_in[35];
    const float* dec_lnfg = (const float*)d_in[36];
    const float* dec_lnfb = (const float*)d_in[37];
    const float* out_b  = (const float*)d_in[39];

    char* wp = (char*)d_ws;
    auto carve = [&](size_t nbytes) {
        void* p = (void*)wp; wp += (nbytes + 255) & ~(size_t)255; return p;
    };

    const long nW = (long)NLay * S2W;
    const long nF = (long)NLay * DFFm * Dm;
    const long nO = 32000L * Dm;

    // bf16 weights: 12 attn mats, 4 ffn mats, out_W (src order below)
    u16* Wb[12];
    for (int i = 0; i < 12; i++) Wb[i] = (u16*)carve((size_t)nW * 2);
    u16* w1E  = (u16*)carve((size_t)nF * 2);
    u16* w2E  = (u16*)carve((size_t)nF * 2);
    u16* w1D  = (u16*)carve((size_t)nF * 2);
    u16* w2D  = (u16*)carve((size_t)nF * 2);
    u16* outW = (u16*)carve((size_t)nO * 2);

    float* x  = (float*)carve((size_t)NTOK * Dm * 4);
    float* y  = (float*)carve((size_t)NTOK * Dm * 4);
    u16* nrm  = (u16*)carve((size_t)NTOK * Dm * 2);
    u16* qkb  = (u16*)carve((size_t)NTOK * 1024 * 2);
    u16* vt   = (u16*)carve((size_t)Bb * Dm * 512 * 2);
    u16* attc = (u16*)carve((size_t)NTOK * Dm * 2);
    u16* h1   = (u16*)carve((size_t)NTOK * DFFm * 2);
    u16* memn = (u16*)carve((size_t)NTOK * Dm * 2);

    // indices into d_in for the 12 attn weight tensors, matching Wb order:
    // eWq eWk eWv eWo | sWq sWk sWv sWo | cWq cWk cWv cWo
    const int wi[12] = {4, 5, 6, 7, 18, 19, 20, 21, 22, 23, 24, 25};
    CvtJobs jobs;
    for (int i = 0; i < 12; i++) {
        jobs.s[i] = (const float*)d_in[wi[i]]; jobs.d[i] = Wb[i]; jobs.n4[i] = nW >> 2;
    }
    jobs.s[12] = (const float*)d_in[8];  jobs.d[12] = w1E;  jobs.n4[12] = nF >> 2;
    jobs.s[13] = (const float*)d_in[10]; jobs.d[13] = w2E;  jobs.n4[13] = nF >> 2;
    jobs.s[14] = (const float*)d_in[26]; jobs.d[14] = w1D;  jobs.n4[14] = nF >> 2;
    jobs.s[15] = (const float*)d_in[28]; jobs.d[15] = w2D;  jobs.n4[15] = nF >> 2;
    jobs.s[16] = (const float*)d_in[38]; jobs.d[16] = outW; jobs.n4[16] = nO >> 2;
    cvt_many<<<dim3(512, 17), 256, 0, stream>>>(jobs);

    const int BIG = 1 << 28;
    u16 *eWq = Wb[0], *eWk = Wb[1], *eWv = Wb[2], *eWo = Wb[3];
    u16 *sWq = Wb[4], *sWk = Wb[5], *sWv = Wb[6], *sWo = Wb[7];
    u16 *cWq = Wb[8], *cWk = Wb[9], *cWv = Wb[10], *cWo = Wb[11];

    // ---------------- Encoder ----------------
    embed_pe<<<4096, 256, 0, stream>>>(src, src_embed, x);
    for (int l = 0; l < NLay; l++) {
        const size_t wo = (size_t)l * S2W;
        ln_rows<<<512, 256, 0, stream>>>(x, enc_ln1g + l * Dm, enc_ln1b + l * Dm, nrm);
        gemm_bt<<<dim3(24, 32), 256, 0, stream>>>(nrm, 512, eWq + wo, eWk + wo, eWv + wo, 512,
            nullptr, qkb, 1024, nullptr, nullptr, 0, 512, 1024, 0, vt);
        attn_fused<<<dim3(8, Hh, Bb), 256, 0, stream>>>(qkb, vt, src, attc, 0);
        gemm_bt<<<dim3(8, 32), 256, 0, stream>>>(attc, 512, eWo + wo, nullptr, nullptr, 512,
            x, nullptr, 512, nullptr, x, 512, 512, BIG, 0, nullptr);
        ln_rows<<<512, 256, 0, stream>>>(x, enc_ln2g + l * Dm, enc_ln2b + l * Dm, nrm);
        gemm_big<<<dim3(16, 16), 256, 0, stream>>>(nrm, 512, w1E + (size_t)l * DFFm * Dm, 512,
            nullptr, h1, DFFm, enc_b1 + l * DFFm, 1, 512);
        gemm_bt<<<dim3(8, 32), 256, 0, stream>>>(h1, DFFm, w2E + (size_t)l * Dm * DFFm,
            nullptr, nullptr, DFFm, x, nullptr, 512, enc_b2 + l * Dm, x, 512, 2048, BIG, 0, nullptr);
    }
    ln_rows<<<512, 256, 0, stream>>>(x, enc_lnfg, enc_lnfb, memn);

    // ---------------- Decoder ----------------
    embed_pe<<<4096, 256, 0, stream>>>(tgt, tgt_embed, y);
    for (int l = 0; l < NLay; l++) {
        const size_t wo = (size_t)l * S2W;
        // self-attention (causal + tgt pad)
        ln_rows<<<512, 256, 0, stream>>>(y, dec_ln1g + l * Dm, dec_ln1b + l * Dm, nrm);
        gemm_bt<<<dim3(24, 32), 256, 0, stream>>>(nrm, 512, sWq + wo, sWk + wo, sWv + wo, 512,
            nullptr, qkb, 1024, nullptr, nullptr, 0, 512, 1024, 0, vt);
        attn_fused<<<dim3(8, Hh, Bb), 256, 0, stream>>>(qkb, vt, tgt, attc, 1);
        gemm_bt<<<dim3(8, 32), 256, 0, stream>>>(attc, 512, sWo + wo, nullptr, nullptr, 512,
            y, nullptr, 512, nullptr, y, 512, 512, BIG, 0, nullptr);
        // cross-attention (src pad), K/V from encoder memory
        ln_rows<<<512, 256, 0, stream>>>(y, dec_ln2g + l * Dm, dec_ln2b + l * Dm, nrm);
        gemm_bt<<<dim3(8, 32), 256, 0, stream>>>(nrm, 512, cWq + wo, nullptr, nullptr, 512,
            nullptr, qkb, 1024, nullptr, nullptr, 0, 512, BIG, 0, nullptr);
        gemm_bt<<<dim3(16, 32), 256, 0, stream>>>(memn, 512, cWk + wo, cWv + wo, nullptr, 512,
            nullptr, qkb, 1024, nullptr, nullptr, 0, 512, 512, 512, vt);
        attn_fused<<<dim3(8, Hh, Bb), 256, 0, stream>>>(qkb, vt, src, attc, 0);
        gemm_bt<<<dim3(8, 32), 256, 0, stream>>>(attc, 512, cWo + wo, nullptr, nullptr, 512,
            y, nullptr, 512, nullptr, y, 512, 512, BIG, 0, nullptr);
        // FFN
        ln_rows<<<512, 256, 0, stream>>>(y, dec_ln3g + l * Dm, dec_ln3b + l * Dm, nrm);
        gemm_big<<<dim3(16, 16), 256, 0, stream>>>(nrm, 512, w1D + (size_t)l * DFFm * Dm, 512,
            nullptr, h1, DFFm, dec_b1 + l * DFFm, 1, 512);
        gemm_bt<<<dim3(8, 32), 256, 0, stream>>>(h1, DFFm, w2D + (size_t)l * Dm * DFFm,
            nullptr, nullptr, DFFm, y, nullptr, 512, dec_b2 + l * Dm, y, 512, 2048, BIG, 0, nullptr);
    }
    ln_rows<<<512, 256, 0, stream>>>(y, dec_lnfg, dec_lnfb, nrm);

    // final projection to vocab: [2048][32000] f32 out
    gemm_big<<<dim3(250, 16), 256, 0, stream>>>(nrm, 512, outW, 512,
        (float*)d_out, nullptr, 32000, out_b, 0, 512);
}

// Round 5
// 1856.912 us; speedup vs baseline: 1.3991x; 1.0335x over previous
//
#include <hip/hip_runtime.h>
#include <hip/hip_bf16.h>
#include <math.h>

// ---------------- problem constants ----------------
#define Dm    512
#define Hh    8
#define NLay  6
#define DFFm  2048
#define Bb    4
#define NTOK  2048          // B * S
#define PADID 1
#define LNEPS 1e-5f
#define S2W   262144        // 512*512 elements (one [512][512] plane)

typedef __attribute__((ext_vector_type(8))) short short8;   // 8 x bf16 (4 VGPRs)
typedef __attribute__((ext_vector_type(4))) float f32x4;
typedef unsigned short u16;

__device__ __forceinline__ u16 f2bf(float f) {
    union { float f; unsigned int i; } x; x.f = f;
    unsigned int r = x.i + 0x7fffu + ((x.i >> 16) & 1u);   // RNE
    return (u16)(r >> 16);
}

// async global->LDS, 16B per lane (dest must be linear-in-lane: base+lane*16)
typedef const __attribute__((address_space(1))) void* as1cv;
typedef __attribute__((address_space(3))) void* as3v;
__device__ __forceinline__ void gl_lds16(const u16* g, u16* l) {
    __builtin_amdgcn_global_load_lds((as1cv)g, (as3v)l, 16, 0, 0);
}

// bijective XCD-chunk swizzle (m204), M fastest within an XCD's chunk so
// consecutive wgids on one XCD share the B panel (its private L2).
__device__ __forceinline__ void swz_tile(int& mt, int& nt) {
    const int nwg  = gridDim.x * gridDim.y;
    const int orig = blockIdx.y * gridDim.x + blockIdx.x;
    const int q8 = nwg >> 3, r8 = nwg & 7;
    const int xcd = orig & 7, idx = orig >> 3;
    const int wgid = (xcd < r8 ? xcd * (q8 + 1) : r8 * (q8 + 1) + (xcd - r8) * q8) + idx;
    const int MT = gridDim.y;
    mt = wgid % MT;
    nt = wgid / MT;
}

// ---- one-launch f32->bf16 conversion of all 17 weight tensors ----
struct CvtJobs {
    const float* s[17];
    u16*         d[17];
    long         n4[17];
};
__global__ __launch_bounds__(256) void cvt_many(CvtJobs j) {
    const int job = blockIdx.y;
    const long n4 = j.n4[job];
    const float* in = j.s[job];
    u16* out = j.d[job];
    long i = (long)blockIdx.x * 256 + threadIdx.x;
    const long stride = (long)gridDim.x * 256;
    for (; i < n4; i += stride) {
        float4 v = ((const float4*)in)[i];
        ushort4 o;
        o.x = f2bf(v.x); o.y = f2bf(v.y); o.z = f2bf(v.z); o.w = f2bf(v.w);
        ((ushort4*)out)[i] = o;
    }
}

// ---------------------------------------------------------------------------
// gemm_bt: C[m,n] = sum_k A[m,k]*B[n,k] (+bias[n]) (+res[m,n])
// 64x64 tile, 4 waves, BK=64, double-buffered, ONE barrier per K-step:
//   prologue stage+barrier; loop { issue next stage; ds_read+8 MFMA; barrier }
// LDS chunk swizzle c^(r&7) (8 chunks/row) -> 2-way bank access (free).
// B selected from 3 part pointers by n0>>9 (512-row parts).
// Epilogue: nl >= vth -> vt[b][nl-vth][s]; else C[ml*csm + nl + koff].
// ---------------------------------------------------------------------------
__global__ __launch_bounds__(256) void gemm_bt(
    const u16* __restrict__ A, int lda,
    const u16* __restrict__ B0, const u16* __restrict__ B1,
    const u16* __restrict__ B2, int ldb,
    float* Cf, u16* Cb, int csm,
    const float* __restrict__ bias,
    const float* res, int ldres,
    int K, int vth, int koff, u16* vtp)
{
    __shared__ u16 As[2][4096];   // 64 rows x 64 k
    __shared__ u16 Bs[2][4096];
    int mt, nt; swz_tile(mt, nt);
    const int m0 = mt << 6, n0 = nt << 6;
    const int t = threadIdx.x, lane = t & 63, wave = t >> 6;
    const int wr = (wave >> 1) << 5, wc = (wave & 1) << 5;
    const int fr = lane & 15, fq = lane >> 4;
    const int srow = t >> 3;                     // 0..31 (second chunk: +32, same swz)
    const int sch  = (t & 7) ^ (srow & 7);       // pre-swizzled source chunk
    const u16* Bsel = (n0 < 512) ? B0 : (n0 < 1024 ? B1 : B2);
    const u16* Ag0 = A + (long)(m0 + srow) * lda + (sch << 3);
    const u16* Ag1 = A + (long)(m0 + 32 + srow) * lda + (sch << 3);
    const u16* Bg0 = Bsel + (long)((n0 & 511) + srow) * ldb + (sch << 3);
    const u16* Bg1 = Bsel + (long)((n0 & 511) + 32 + srow) * ldb + (sch << 3);

    f32x4 acc[2][2];
    #pragma unroll
    for (int i = 0; i < 2; i++)
        #pragma unroll
        for (int j = 0; j < 2; j++) acc[i][j] = (f32x4){0.f, 0.f, 0.f, 0.f};

    const int nk = K >> 6;
    gl_lds16(Ag0, &As[0][t << 3]);
    gl_lds16(Ag1, &As[0][(t + 256) << 3]);
    gl_lds16(Bg0, &Bs[0][t << 3]);
    gl_lds16(Bg1, &Bs[0][(t + 256) << 3]);
    __syncthreads();
    for (int ki = 0; ki < nk; ki++) {
        const int cur = ki & 1;
        if (ki + 1 < nk) {
            const int ko = (ki + 1) << 6;
            gl_lds16(Ag0 + ko, &As[cur ^ 1][t << 3]);
            gl_lds16(Ag1 + ko, &As[cur ^ 1][(t + 256) << 3]);
            gl_lds16(Bg0 + ko, &Bs[cur ^ 1][t << 3]);
            gl_lds16(Bg1 + ko, &Bs[cur ^ 1][(t + 256) << 3]);
        }
        const int r0 = wr + fr, r1 = wr + 16 + fr;
        const int c0 = wc + fr, c1 = wc + 16 + fr;
        #pragma unroll
        for (int h = 0; h < 2; h++) {
            const int lc = fq | (h << 2);
            short8 af0 = *(const short8*)&As[cur][(r0 << 6) + ((lc ^ (r0 & 7)) << 3)];
            short8 af1 = *(const short8*)&As[cur][(r1 << 6) + ((lc ^ (r1 & 7)) << 3)];
            short8 bf0 = *(const short8*)&Bs[cur][(c0 << 6) + ((lc ^ (c0 & 7)) << 3)];
            short8 bf1 = *(const short8*)&Bs[cur][(c1 << 6) + ((lc ^ (c1 & 7)) << 3)];
            acc[0][0] = __builtin_amdgcn_mfma_f32_16x16x32_bf16(af0, bf0, acc[0][0], 0, 0, 0);
            acc[0][1] = __builtin_amdgcn_mfma_f32_16x16x32_bf16(af0, bf1, acc[0][1], 0, 0, 0);
            acc[1][0] = __builtin_amdgcn_mfma_f32_16x16x32_bf16(af1, bf0, acc[1][0], 0, 0, 0);
            acc[1][1] = __builtin_amdgcn_mfma_f32_16x16x32_bf16(af1, bf1, acc[1][1], 0, 0, 0);
        }
        __syncthreads();
    }

    #pragma unroll
    for (int i = 0; i < 2; i++) {
        #pragma unroll
        for (int j = 0; j < 2; j++) {
            const int nl  = n0 + wc + (j << 4) + fr;
            const int mlb = m0 + wr + (i << 4) + (fq << 2);
            const float bsv = bias ? bias[nl] : 0.f;
            #pragma unroll
            for (int r = 0; r < 4; r++) {
                const int ml = mlb + r;
                float v = acc[i][j][r] + bsv;
                if (nl >= vth) {
                    vtp[(long)(ml >> 9) * S2W + (long)(nl - vth) * 512 + (ml & 511)] = f2bf(v);
                } else {
                    long ci = (long)ml * csm + nl + koff;
                    if (res) v += res[(long)ml * ldres + nl];
                    if (Cf) Cf[ci] = v;
                    if (Cb) Cb[ci] = f2bf(v);
                }
            }
        }
    }
}

// ---------------------------------------------------------------------------
// gemm_big: 128x128 tile, 4 waves each 64x64, BK=32, double-buffered,
// ONE barrier per K-step; LDS chunk swizzle c^((r>>1)&3) -> conflict-free.
// ---------------------------------------------------------------------------
__global__ __launch_bounds__(256) void gemm_big(
    const u16* __restrict__ A, int lda,
    const u16* __restrict__ B, int ldb,
    float* Cf, u16* Cb, int ldc,
    const float* __restrict__ bias, int relu, int K)
{
    __shared__ u16 As[2][4096];   // 128 rows x 32 k
    __shared__ u16 Bs[2][4096];
    int mt, nt; swz_tile(mt, nt);
    const int m0 = mt << 7, n0 = nt << 7;
    const int t = threadIdx.x, lane = t & 63, wave = t >> 6;
    const int wr = (wave >> 1) << 6, wc = (wave & 1) << 6;
    const int fr = lane & 15, fq = lane >> 4;
    const int srow = t >> 2;                          // 0..63 (second: +64, same swz)
    const int sch  = (t & 3) ^ ((srow >> 1) & 3);     // pre-swizzled source chunk
    const u16* Ag0 = A + (long)(m0 + srow) * lda + (sch << 3);
    const u16* Ag1 = A + (long)(m0 + 64 + srow) * lda + (sch << 3);
    const u16* Bg0 = B + (long)(n0 + srow) * ldb + (sch << 3);
    const u16* Bg1 = B + (long)(n0 + 64 + srow) * ldb + (sch << 3);

    f32x4 acc[4][4];
    #pragma unroll
    for (int i = 0; i < 4; i++)
        #pragma unroll
        for (int j = 0; j < 4; j++) acc[i][j] = (f32x4){0.f, 0.f, 0.f, 0.f};

    const int nk = K >> 5;
    gl_lds16(Ag0, &As[0][t << 3]);
    gl_lds16(Ag1, &As[0][(t + 256) << 3]);
    gl_lds16(Bg0, &Bs[0][t << 3]);
    gl_lds16(Bg1, &Bs[0][(t + 256) << 3]);
    __syncthreads();
    for (int ki = 0; ki < nk; ki++) {
        const int cur = ki & 1;
        if (ki + 1 < nk) {
            const int ko = (ki + 1) << 5;
            gl_lds16(Ag0 + ko, &As[cur ^ 1][t << 3]);
            gl_lds16(Ag1 + ko, &As[cur ^ 1][(t + 256) << 3]);
            gl_lds16(Bg0 + ko, &Bs[cur ^ 1][t << 3]);
            gl_lds16(Bg1 + ko, &Bs[cur ^ 1][(t + 256) << 3]);
        }
        short8 af[4], bf[4];
        #pragma unroll
        for (int i = 0; i < 4; i++) {
            const int r = wr + (i << 4) + fr;
            af[i] = *(const short8*)&As[cur][(r << 5) + ((fq ^ ((r >> 1) & 3)) << 3)];
        }
        #pragma unroll
        for (int j = 0; j < 4; j++) {
            const int c = wc + (j << 4) + fr;
            bf[j] = *(const short8*)&Bs[cur][(c << 5) + ((fq ^ ((c >> 1) & 3)) << 3)];
        }
        #pragma unroll
        for (int i = 0; i < 4; i++)
            #pragma unroll
            for (int j = 0; j < 4; j++)
                acc[i][j] = __builtin_amdgcn_mfma_f32_16x16x32_bf16(af[i], bf[j], acc[i][j], 0, 0, 0);
        __syncthreads();
    }

    #pragma unroll
    for (int i = 0; i < 4; i++) {
        #pragma unroll
        for (int j = 0; j < 4; j++) {
            const int nl  = n0 + wc + (j << 4) + fr;
            const int mlb = m0 + wr + (i << 4) + (fq << 2);
            const float bsv = bias ? bias[nl] : 0.f;
            #pragma unroll
            for (int r = 0; r < 4; r++) {
                float v = acc[i][j][r] + bsv;
                if (relu) v = fmaxf(v, 0.f);
                long ci = (long)(mlb + r) * ldc + nl;
                if (Cf) Cf[ci] = v;
                if (Cb) Cb[ci] = f2bf(v);
            }
        }
    }
}

// ---------------------------------------------------------------------------
// Fused attention: block per (q-tile 64, head, batch), 4 waves x 16 q-rows.
// K/V tiles in LDS, double-buffered, ONE barrier per tile; sources
// pre-swizzled (c' = c ^ (row&7)) so swizzled ds_reads are conflict-free.
// ---------------------------------------------------------------------------
__global__ __launch_bounds__(256) void attn_fused(
    const u16* __restrict__ qkb, const u16* __restrict__ vt,
    const int* __restrict__ ids, u16* __restrict__ attc, int causal)
{
    __shared__ u16 Ks[2][4096];
    __shared__ u16 Vs[2][4096];
    __shared__ short Ps[4][16][72];
    const int t = threadIdx.x, lane = t & 63, w = t >> 6;
    const int fr = lane & 15, fq = lane >> 4;
    const int q0 = blockIdx.x << 6, h = blockIdx.y, b = blockIdx.z;

    const u16* qp = qkb + (long)(b * 512 + q0 + (w << 4) + fr) * 1024 + h * 64 + (fq << 3);
    short8 aq0 = *(const short8*)qp;
    short8 aq1 = *(const short8*)(qp + 32);

    // staging: 512 16B-chunks per tile; thread t stages chunks t and t+256
    // (rows sr, sr+32 share the same swizzled source column).
    const int sr = t >> 3, sc = (t & 7) ^ (sr & 7);
    const u16* kg0 = qkb + (long)(b * 512 + sr) * 1024 + 512 + h * 64 + (sc << 3);
    const u16* kg1 = kg0 + 32L * 1024;
    const u16* vg0 = vt + (long)b * S2W + (long)(h * 64 + sr) * 512 + (sc << 3);
    const u16* vg1 = vg0 + 32L * 512;

    // pad mask for all 512 keys (bit kt*4+j), computed once
    unsigned pmask = 0;
    #pragma unroll
    for (int kt = 0; kt < 8; kt++)
        #pragma unroll
        for (int j = 0; j < 4; j++)
            if (ids[b * 512 + (kt << 6) + (j << 4) + fr] == PADID)
                pmask |= 1u << ((kt << 2) + j);

    float m[4], l[4]; f32x4 oc[4];
    #pragma unroll
    for (int r = 0; r < 4; r++) { m[r] = -INFINITY; l[r] = 0.f; oc[r] = (f32x4){0.f,0.f,0.f,0.f}; }

    const int lastkt = causal ? (q0 >> 6) : 7;
    auto stage = [&](int kt, int buf) {
        const long so = (long)(kt << 6);
        gl_lds16(kg0 + so * 1024, &Ks[buf][t << 3]);
        gl_lds16(kg1 + so * 1024, &Ks[buf][(t + 256) << 3]);
        gl_lds16(vg0 + so, &Vs[buf][t << 3]);
        gl_lds16(vg1 + so, &Vs[buf][(t + 256) << 3]);
    };
    stage(0, 0);
    __syncthreads();

    for (int kt = 0; kt <= lastkt; kt++) {
        const int cur = kt & 1;
        if (kt < lastkt) stage(kt + 1, cur ^ 1);

        f32x4 sc4[4];
        #pragma unroll
        for (int j = 0; j < 4; j++) sc4[j] = (f32x4){0.f,0.f,0.f,0.f};
        #pragma unroll
        for (int j = 0; j < 4; j++) {
            const int rr = (j << 4) + fr;
            short8 bk0 = *(const short8*)&Ks[cur][rr * 64 + ((fq ^ (rr & 7)) << 3)];
            short8 bk1 = *(const short8*)&Ks[cur][rr * 64 + (((fq | 4) ^ (rr & 7)) << 3)];
            sc4[j] = __builtin_amdgcn_mfma_f32_16x16x32_bf16(aq0, bk0, sc4[j], 0, 0, 0);
            sc4[j] = __builtin_amdgcn_mfma_f32_16x16x32_bf16(aq1, bk1, sc4[j], 0, 0, 0);
        }
        const int s0 = kt << 6;
        #pragma unroll
        for (int r = 0; r < 4; r++) {
            const int qa = q0 + (w << 4) + (fq << 2) + r;
            float mx = -INFINITY;
            #pragma unroll
            for (int j = 0; j < 4; j++) {
                bool msk = ((pmask >> ((kt << 2) + j)) & 1) ||
                           (causal && (s0 + (j << 4) + fr) > qa);
                float sv = msk ? -INFINITY : sc4[j][r] * 0.125f;
                sc4[j][r] = sv;
                mx = fmaxf(mx, sv);
            }
            mx = fmaxf(mx, __shfl_xor(mx, 1)); mx = fmaxf(mx, __shfl_xor(mx, 2));
            mx = fmaxf(mx, __shfl_xor(mx, 4)); mx = fmaxf(mx, __shfl_xor(mx, 8));
            float mnew  = fmaxf(m[r], mx);
            float scale = (mnew == -INFINITY) ? 1.f : __expf(m[r] - mnew);
            float ps = 0.f;
            #pragma unroll
            for (int j = 0; j < 4; j++) {
                float p = (sc4[j][r] == -INFINITY) ? 0.f : __expf(sc4[j][r] - mnew);
                sc4[j][r] = p; ps += p;
            }
            ps += __shfl_xor(ps, 1); ps += __shfl_xor(ps, 2);
            ps += __shfl_xor(ps, 4); ps += __shfl_xor(ps, 8);
            l[r] = l[r] * scale + ps;
            m[r] = mnew;
            #pragma unroll
            for (int j2 = 0; j2 < 4; j2++) oc[j2][r] *= scale;
        }
        #pragma unroll
        for (int r = 0; r < 4; r++)
            #pragma unroll
            for (int j = 0; j < 4; j++)
                Ps[w][(fq << 2) + r][(j << 4) + fr] = (short)f2bf(sc4[j][r]);
        #pragma unroll
        for (int kc = 0; kc < 2; kc++) {
            short8 pa = *(const short8*)&Ps[w][fr][(kc << 5) + (fq << 3)];
            #pragma unroll
            for (int j2 = 0; j2 < 4; j2++) {
                const int rd = (j2 << 4) + fr;
                const int cch = (((kc << 2) | fq) ^ (rd & 7));
                short8 bv = *(const short8*)&Vs[cur][rd * 64 + (cch << 3)];
                oc[j2] = __builtin_amdgcn_mfma_f32_16x16x32_bf16(pa, bv, oc[j2], 0, 0, 0);
            }
        }
        __syncthreads();
    }

    float inv[4];
    #pragma unroll
    for (int r = 0; r < 4; r++) inv[r] = (l[r] > 0.f) ? 1.f / l[r] : 0.f;
    #pragma unroll
    for (int j2 = 0; j2 < 4; j2++)
        #pragma unroll
        for (int r = 0; r < 4; r++)
            attc[(long)(b * 512 + q0 + (w << 4) + (fq << 2) + r) * 512 + h * 64 + (j2 << 4) + fr]
                = f2bf(oc[j2][r] * inv[r]);
}

// LayerNorm over D=512: 4 rows/block (wave per row). f32 in -> bf16 out.
__global__ __launch_bounds__(256) void ln_rows(
    const float* __restrict__ x, const float* __restrict__ g,
    const float* __restrict__ b, u16* __restrict__ out)
{
    int row  = blockIdx.x * 4 + (threadIdx.x >> 6);
    int lane = threadIdx.x & 63;
    const float* xr = x + (long)row * Dm;
    float v[8]; float s = 0.f;
    #pragma unroll
    for (int i = 0; i < 8; i++) { v[i] = xr[lane + (i << 6)]; s += v[i]; }
    #pragma unroll
    for (int o = 32; o > 0; o >>= 1) s += __shfl_xor(s, o);
    float mean = s * (1.f / 512.f);
    float q = 0.f;
    #pragma unroll
    for (int i = 0; i < 8; i++) { float d = v[i] - mean; q += d * d; }
    #pragma unroll
    for (int o = 32; o > 0; o >>= 1) q += __shfl_xor(q, o);
    float rinv = rsqrtf(q * (1.f / 512.f) + LNEPS);
    u16* orow = out + (long)row * Dm;
    #pragma unroll
    for (int i = 0; i < 8; i++) {
        int c = lane + (i << 6);
        orow[c] = f2bf((v[i] - mean) * rinv * g[c] + b[c]);
    }
}

// x[b,s,:] = embed[id]*sqrt(D) + PE(s,:)   (f32 in/out)
__global__ __launch_bounds__(256) void embed_pe(
    const int* __restrict__ ids, const float* __restrict__ emb,
    float* __restrict__ out)
{
    int idx = blockIdx.x * 256 + threadIdx.x;   // NTOK*512 = 2^20
    int d   = idx & 511;
    int tok = idx >> 9;
    int s   = tok & 511;
    int id  = ids[tok];
    float val = emb[(long)id * Dm + d] * 22.62741699796952f;     // sqrt(512)
    int i2 = d >> 1;
    float dv  = expf((float)(i2 << 1) * (-9.210340371976184f / 512.f));
    float ang = (float)s * dv;
    val += (d & 1) ? cosf(ang) : sinf(ang);
    out[idx] = val;
}

// ---------------------------------------------------------------------------
extern "C" void kernel_launch(void* const* d_in, const int* in_sizes, int n_in,
                              void* d_out, int out_size, void* d_ws, size_t ws_size,
                              hipStream_t stream)
{
    (void)in_sizes; (void)n_in; (void)out_size; (void)ws_size;
    const int*   src       = (const int*)d_in[0];
    const int*   tgt       = (const int*)d_in[1];
    const float* src_embed = (const float*)d_in[2];
    const float* tgt_embed = (const float*)d_in[3];
    const float* enc_b1  = (const float*)d_in[9];
    const float* enc_b2  = (const float*)d_in[11];
    const float* enc_ln1g = (const float*)d_in[12];
    const float* enc_ln1b = (const float*)d_in[13];
    const float* enc_ln2g = (const float*)d_in[14];
    const float* enc_ln2b = (const float*)d_in[15];
    const float* enc_lnfg = (const float*)d_in[16];
    const float* enc_lnfb = (const float*)d_in[17];
    const float* dec_b1  = (const float*)d_in[27];
    const float* dec_b2  = (const float*)d_in[29];
    const float* dec_ln1g = (const float*)d_in[30];
    const float* dec_ln1b = (const float*)d_in[31];
    const float* dec_ln2g = (const float*)d_in[32];
    const float* dec_ln2b = (const float*)d_in[33];
    const float* dec_ln3g = (const float*)d_in[34];
    const float* dec_ln3b = (const float*)d_in[35];
    const float* dec_lnfg = (const float*)d_in[36];
    const float* dec_lnfb = (const float*)d_in[37];
    const float* out_b  = (const float*)d_in[39];

    char* wp = (char*)d_ws;
    auto carve = [&](size_t nbytes) {
        void* p = (void*)wp; wp += (nbytes + 255) & ~(size_t)255; return p;
    };

    const long nW = (long)NLay * S2W;
    const long nF = (long)NLay * DFFm * Dm;
    const long nO = 32000L * Dm;

    // bf16 weights: 12 attn mats, 4 ffn mats, out_W
    u16* Wb[12];
    for (int i = 0; i < 12; i++) Wb[i] = (u16*)carve((size_t)nW * 2);
    u16* w1E  = (u16*)carve((size_t)nF * 2);
    u16* w2E  = (u16*)carve((size_t)nF * 2);
    u16* w1D  = (u16*)carve((size_t)nF * 2);
    u16* w2D  = (u16*)carve((size_t)nF * 2);
    u16* outW = (u16*)carve((size_t)nO * 2);

    float* x  = (float*)carve((size_t)NTOK * Dm * 4);
    float* y  = (float*)carve((size_t)NTOK * Dm * 4);
    u16* nrm  = (u16*)carve((size_t)NTOK * Dm * 2);
    u16* qkb  = (u16*)carve((size_t)NTOK * 1024 * 2);
    u16* vt   = (u16*)carve((size_t)Bb * Dm * 512 * 2);
    u16* attc = (u16*)carve((size_t)NTOK * Dm * 2);
    u16* h1   = (u16*)carve((size_t)NTOK * DFFm * 2);
    u16* memn = (u16*)carve((size_t)NTOK * Dm * 2);

    // d_in indices for the 12 attn weight tensors, matching Wb order:
    // eWq eWk eWv eWo | sWq sWk sWv sWo | cWq cWk cWv cWo
    const int wi[12] = {4, 5, 6, 7, 18, 19, 20, 21, 22, 23, 24, 25};
    CvtJobs jobs;
    for (int i = 0; i < 12; i++) {
        jobs.s[i] = (const float*)d_in[wi[i]]; jobs.d[i] = Wb[i]; jobs.n4[i] = nW >> 2;
    }
    jobs.s[12] = (const float*)d_in[8];  jobs.d[12] = w1E;  jobs.n4[12] = nF >> 2;
    jobs.s[13] = (const float*)d_in[10]; jobs.d[13] = w2E;  jobs.n4[13] = nF >> 2;
    jobs.s[14] = (const float*)d_in[26]; jobs.d[14] = w1D;  jobs.n4[14] = nF >> 2;
    jobs.s[15] = (const float*)d_in[28]; jobs.d[15] = w2D;  jobs.n4[15] = nF >> 2;
    jobs.s[16] = (const float*)d_in[38]; jobs.d[16] = outW; jobs.n4[16] = nO >> 2;
    cvt_many<<<dim3(512, 17), 256, 0, stream>>>(jobs);

    const int BIG = 1 << 28;
    u16 *eWq = Wb[0], *eWk = Wb[1], *eWv = Wb[2], *eWo = Wb[3];
    u16 *sWq = Wb[4], *sWk = Wb[5], *sWv = Wb[6], *sWo = Wb[7];
    u16 *cWq = Wb[8], *cWk = Wb[9], *cWv = Wb[10], *cWo = Wb[11];

    // ---------------- Encoder ----------------
    embed_pe<<<4096, 256, 0, stream>>>(src, src_embed, x);
    for (int l = 0; l < NLay; l++) {
        const size_t wo = (size_t)l * S2W;
        ln_rows<<<512, 256, 0, stream>>>(x, enc_ln1g + l * Dm, enc_ln1b + l * Dm, nrm);
        gemm_bt<<<dim3(24, 32), 256, 0, stream>>>(nrm, 512, eWq + wo, eWk + wo, eWv + wo, 512,
            nullptr, qkb, 1024, nullptr, nullptr, 0, 512, 1024, 0, vt);
        attn_fused<<<dim3(8, Hh, Bb), 256, 0, stream>>>(qkb, vt, src, attc, 0);
        gemm_bt<<<dim3(8, 32), 256, 0, stream>>>(attc, 512, eWo + wo, nullptr, nullptr, 512,
            x, nullptr, 512, nullptr, x, 512, 512, BIG, 0, nullptr);
        ln_rows<<<512, 256, 0, stream>>>(x, enc_ln2g + l * Dm, enc_ln2b + l * Dm, nrm);
        gemm_big<<<dim3(16, 16), 256, 0, stream>>>(nrm, 512, w1E + (size_t)l * DFFm * Dm, 512,
            nullptr, h1, DFFm, enc_b1 + l * DFFm, 1, 512);
        gemm_bt<<<dim3(8, 32), 256, 0, stream>>>(h1, DFFm, w2E + (size_t)l * Dm * DFFm,
            nullptr, nullptr, DFFm, x, nullptr, 512, enc_b2 + l * Dm, x, 512, 2048, BIG, 0, nullptr);
    }
    ln_rows<<<512, 256, 0, stream>>>(x, enc_lnfg, enc_lnfb, memn);

    // ---------------- Decoder ----------------
    embed_pe<<<4096, 256, 0, stream>>>(tgt, tgt_embed, y);
    for (int l = 0; l < NLay; l++) {
        const size_t wo = (size_t)l * S2W;
        // self-attention (causal + tgt pad)
        ln_rows<<<512, 256, 0, stream>>>(y, dec_ln1g + l * Dm, dec_ln1b + l * Dm, nrm);
        gemm_bt<<<dim3(24, 32), 256, 0, stream>>>(nrm, 512, sWq + wo, sWk + wo, sWv + wo, 512,
            nullptr, qkb, 1024, nullptr, nullptr, 0, 512, 1024, 0, vt);
        attn_fused<<<dim3(8, Hh, Bb), 256, 0, stream>>>(qkb, vt, tgt, attc, 1);
        gemm_bt<<<dim3(8, 32), 256, 0, stream>>>(attc, 512, sWo + wo, nullptr, nullptr, 512,
            y, nullptr, 512, nullptr, y, 512, 512, BIG, 0, nullptr);
        // cross-attention (src pad), K/V from encoder memory
        ln_rows<<<512, 256, 0, stream>>>(y, dec_ln2g + l * Dm, dec_ln2b + l * Dm, nrm);
        gemm_bt<<<dim3(8, 32), 256, 0, stream>>>(nrm, 512, cWq + wo, nullptr, nullptr, 512,
            nullptr, qkb, 1024, nullptr, nullptr, 0, 512, BIG, 0, nullptr);
        gemm_bt<<<dim3(16, 32), 256, 0, stream>>>(memn, 512, cWk + wo, cWv + wo, nullptr, 512,
            nullptr, qkb, 1024, nullptr, nullptr, 0, 512, 512, 512, vt);
        attn_fused<<<dim3(8, Hh, Bb), 256, 0, stream>>>(qkb, vt, src, attc, 0);
        gemm_bt<<<dim3(8, 32), 256, 0, stream>>>(attc, 512, cWo + wo, nullptr, nullptr, 512,
            y, nullptr, 512, nullptr, y, 512, 512, BIG, 0, nullptr);
        // FFN
        ln_rows<<<512, 256, 0, stream>>>(y, dec_ln3g + l * Dm, dec_ln3b + l * Dm, nrm);
        gemm_big<<<dim3(16, 16), 256, 0, stream>>>(nrm, 512, w1D + (size_t)l * DFFm * Dm, 512,
            nullptr, h1, DFFm, dec_b1 + l * DFFm, 1, 512);
        gemm_bt<<<dim3(8, 32), 256, 0, stream>>>(h1, DFFm, w2D + (size_t)l * Dm * DFFm,
            nullptr, nullptr, DFFm, y, nullptr, 512, dec_b2 + l * Dm, y, 512, 2048, BIG, 0, nullptr);
    }
    ln_rows<<<512, 256, 0, stream>>>(y, dec_lnfg, dec_lnfb, nrm);

    // final projection to vocab: [2048][32000] f32 out
    gemm_big<<<dim3(250, 16), 256, 0, stream>>>(nrm, 512, outW, 512,
        (float*)d_out, nullptr, 32000, out_b, 0, 512);
}

// Round 7
// 1647.834 us; speedup vs baseline: 1.5767x; 1.1269x over previous
//
#include <hip/hip_runtime.h>
#include <hip/hip_bf16.h>
#include <math.h>

// ---------------- problem constants ----------------
#define Dm    512
#define Hh    8
#define NLay  6
#define DFFm  2048
#define Bb    4
#define NTOK  2048          // B * S
#define PADID 1
#define LNEPS 1e-5f
#define S2W   262144        // 512*512 elements (one [512][512] plane)

typedef __attribute__((ext_vector_type(8))) short short8;   // 8 x bf16 (4 VGPRs)
typedef __attribute__((ext_vector_type(4))) float f32x4;
typedef unsigned short u16;

__device__ __forceinline__ u16 f2bf(float f) {
    union { float f; unsigned int i; } x; x.f = f;
    unsigned int r = x.i + 0x7fffu + ((x.i >> 16) & 1u);   // RNE
    return (u16)(r >> 16);
}

// async global->LDS, 16B per lane (dest must be linear-in-lane: base+lane*16)
typedef const __attribute__((address_space(1))) void* as1cv;
typedef __attribute__((address_space(3))) void* as3v;
__device__ __forceinline__ void gl_lds16(const u16* g, u16* l) {
    __builtin_amdgcn_global_load_lds((as1cv)g, (as3v)l, 16, 0, 0);
}

// bijective XCD-chunk swizzle (m204), M fastest within an XCD's chunk so
// consecutive wgids on one XCD share the B panel (its private L2).
__device__ __forceinline__ void swz_tile(int& mt, int& nt) {
    const int nwg  = gridDim.x * gridDim.y;
    const int orig = blockIdx.y * gridDim.x + blockIdx.x;
    const int q8 = nwg >> 3, r8 = nwg & 7;
    const int xcd = orig & 7, idx = orig >> 3;
    const int wgid = (xcd < r8 ? xcd * (q8 + 1) : r8 * (q8 + 1) + (xcd - r8) * q8) + idx;
    const int MT = gridDim.y;
    mt = wgid % MT;
    nt = wgid / MT;
}

// ---- one-launch f32->bf16 conversion of all 17 weight tensors ----
struct CvtJobs {
    const float* s[17];
    u16*         d[17];
    long         n4[17];
};
__global__ __launch_bounds__(256) void cvt_many(CvtJobs j) {
    const int job = blockIdx.y;
    const long n4 = j.n4[job];
    const float* in = j.s[job];
    u16* out = j.d[job];
    long i = (long)blockIdx.x * 256 + threadIdx.x;
    const long stride = (long)gridDim.x * 256;
    for (; i < n4; i += stride) {
        float4 v = ((const float4*)in)[i];
        ushort4 o;
        o.x = f2bf(v.x); o.y = f2bf(v.y); o.z = f2bf(v.z); o.w = f2bf(v.w);
        ((ushort4*)out)[i] = o;
    }
}

// ---------------------------------------------------------------------------
// gemm_bt: C[m,n] = sum_k A[m,k]*B[n,k] (+bias[n]) (+relu)
// 64x64 tile, 4 waves, BK=64, double-buffered, one barrier per K-step.
// Per-512-col part: p = n0>>9 selects (A0..A2, B0..B2); if B1==nullptr the
// B matrix is contiguous (ldb rows) and n indexes B0 directly.
// Split-K: grid.z = ns slices of Kc each; ns>1 -> unsafeAtomicAdd f32 into Cf
// (bias added by slice 0 only; relu/vt/Cb unsupported in that mode).
// ns==1 epilogue: nl >= vth -> vt[b][nl-vth][s]; else C[ml*csm + nl + koff].
// ---------------------------------------------------------------------------
__global__ __launch_bounds__(256) void gemm_bt(
    const u16* __restrict__ A0, const u16* __restrict__ A1,
    const u16* __restrict__ A2, int lda,
    const u16* __restrict__ B0, const u16* __restrict__ B1,
    const u16* __restrict__ B2, int ldb,
    float* Cf, u16* Cb, int csm,
    const float* __restrict__ bias, int relu,
    int Kc, int ns, int vth, int koff, u16* vtp)
{
    __shared__ u16 As[2][4096];   // 64 rows x 64 k
    __shared__ u16 Bs[2][4096];
    int mt, nt; swz_tile(mt, nt);
    const int m0 = mt << 6, n0 = nt << 6;
    const int t = threadIdx.x, lane = t & 63, wave = t >> 6;
    const int wr = (wave >> 1) << 5, wc = (wave & 1) << 5;
    const int fr = lane & 15, fq = lane >> 4;
    const int srow = t >> 3;                     // 0..31 (second chunk: +32)
    const int sch  = (t & 7) ^ (srow & 7);       // pre-swizzled source chunk

    const int p = n0 >> 9;
    const u16* Amat = (p == 0) ? A0 : (p == 1 ? A1 : A2);
    const u16* Bmat; int nb;
    if (B1) { Bmat = (p == 0) ? B0 : (p == 1 ? B1 : B2); nb = n0 & 511; }
    else    { Bmat = B0; nb = n0; }
    const long kb = (long)blockIdx.z * Kc;

    const u16* Ag0 = Amat + (long)(m0 + srow) * lda + kb + (sch << 3);
    const u16* Ag1 = Ag0 + 32L * lda;
    const u16* Bg0 = Bmat + (long)(nb + srow) * ldb + kb + (sch << 3);
    const u16* Bg1 = Bg0 + 32L * ldb;

    f32x4 acc[2][2];
    #pragma unroll
    for (int i = 0; i < 2; i++)
        #pragma unroll
        for (int j = 0; j < 2; j++) acc[i][j] = (f32x4){0.f, 0.f, 0.f, 0.f};

    const int nk = Kc >> 6;
    gl_lds16(Ag0, &As[0][t << 3]);
    gl_lds16(Ag1, &As[0][(t + 256) << 3]);
    gl_lds16(Bg0, &Bs[0][t << 3]);
    gl_lds16(Bg1, &Bs[0][(t + 256) << 3]);
    __syncthreads();
    for (int ki = 0; ki < nk; ki++) {
        const int cur = ki & 1;
        if (ki + 1 < nk) {
            const int ko = (ki + 1) << 6;
            gl_lds16(Ag0 + ko, &As[cur ^ 1][t << 3]);
            gl_lds16(Ag1 + ko, &As[cur ^ 1][(t + 256) << 3]);
            gl_lds16(Bg0 + ko, &Bs[cur ^ 1][t << 3]);
            gl_lds16(Bg1 + ko, &Bs[cur ^ 1][(t + 256) << 3]);
        }
        const int r0 = wr + fr, r1 = wr + 16 + fr;
        const int c0 = wc + fr, c1 = wc + 16 + fr;
        #pragma unroll
        for (int h = 0; h < 2; h++) {
            const int lc = fq | (h << 2);
            short8 af0 = *(const short8*)&As[cur][(r0 << 6) + ((lc ^ (r0 & 7)) << 3)];
            short8 af1 = *(const short8*)&As[cur][(r1 << 6) + ((lc ^ (r1 & 7)) << 3)];
            short8 bf0 = *(const short8*)&Bs[cur][(c0 << 6) + ((lc ^ (c0 & 7)) << 3)];
            short8 bf1 = *(const short8*)&Bs[cur][(c1 << 6) + ((lc ^ (c1 & 7)) << 3)];
            acc[0][0] = __builtin_amdgcn_mfma_f32_16x16x32_bf16(af0, bf0, acc[0][0], 0, 0, 0);
            acc[0][1] = __builtin_amdgcn_mfma_f32_16x16x32_bf16(af0, bf1, acc[0][1], 0, 0, 0);
            acc[1][0] = __builtin_amdgcn_mfma_f32_16x16x32_bf16(af1, bf0, acc[1][0], 0, 0, 0);
            acc[1][1] = __builtin_amdgcn_mfma_f32_16x16x32_bf16(af1, bf1, acc[1][1], 0, 0, 0);
        }
        __syncthreads();
    }

    #pragma unroll
    for (int i = 0; i < 2; i++) {
        #pragma unroll
        for (int j = 0; j < 2; j++) {
            const int nl  = n0 + wc + (j << 4) + fr;
            const int mlb = m0 + wr + (i << 4) + (fq << 2);
            const float bsv = bias ? bias[nl] : 0.f;
            #pragma unroll
            for (int r = 0; r < 4; r++) {
                const int ml = mlb + r;
                if (ns > 1) {
                    float v = acc[i][j][r] + (blockIdx.z == 0 ? bsv : 0.f);
                    unsafeAtomicAdd(&Cf[(long)ml * csm + nl + koff], v);
                } else {
                    float v = acc[i][j][r] + bsv;
                    if (nl >= vth) {
                        vtp[(long)(ml >> 9) * S2W + (long)(nl - vth) * 512 + (ml & 511)] = f2bf(v);
                    } else {
                        if (relu) v = fmaxf(v, 0.f);
                        long ci = (long)ml * csm + nl + koff;
                        if (Cf) Cf[ci] = v;
                        if (Cb) Cb[ci] = f2bf(v);
                    }
                }
            }
        }
    }
}

// ---------------------------------------------------------------------------
// gemm_big: 128x128 tile, 4 waves each 64x64, BK=32, double-buffered,
// one barrier per K-step; LDS chunk swizzle c^((r>>1)&3) -> conflict-free.
// Used for the [2048 x 32000] logits GEMM only.
// ---------------------------------------------------------------------------
__global__ __launch_bounds__(256) void gemm_big(
    const u16* __restrict__ A, int lda,
    const u16* __restrict__ B, int ldb,
    float* Cf, u16* Cb, int ldc,
    const float* __restrict__ bias, int relu, int K)
{
    __shared__ u16 As[2][4096];   // 128 rows x 32 k
    __shared__ u16 Bs[2][4096];
    int mt, nt; swz_tile(mt, nt);
    const int m0 = mt << 7, n0 = nt << 7;
    const int t = threadIdx.x, lane = t & 63, wave = t >> 6;
    const int wr = (wave >> 1) << 6, wc = (wave & 1) << 6;
    const int fr = lane & 15, fq = lane >> 4;
    const int srow = t >> 2;
    const int sch  = (t & 3) ^ ((srow >> 1) & 3);
    const u16* Ag0 = A + (long)(m0 + srow) * lda + (sch << 3);
    const u16* Ag1 = A + (long)(m0 + 64 + srow) * lda + (sch << 3);
    const u16* Bg0 = B + (long)(n0 + srow) * ldb + (sch << 3);
    const u16* Bg1 = B + (long)(n0 + 64 + srow) * ldb + (sch << 3);

    f32x4 acc[4][4];
    #pragma unroll
    for (int i = 0; i < 4; i++)
        #pragma unroll
        for (int j = 0; j < 4; j++) acc[i][j] = (f32x4){0.f, 0.f, 0.f, 0.f};

    const int nk = K >> 5;
    gl_lds16(Ag0, &As[0][t << 3]);
    gl_lds16(Ag1, &As[0][(t + 256) << 3]);
    gl_lds16(Bg0, &Bs[0][t << 3]);
    gl_lds16(Bg1, &Bs[0][(t + 256) << 3]);
    __syncthreads();
    for (int ki = 0; ki < nk; ki++) {
        const int cur = ki & 1;
        if (ki + 1 < nk) {
            const int ko = (ki + 1) << 5;
            gl_lds16(Ag0 + ko, &As[cur ^ 1][t << 3]);
            gl_lds16(Ag1 + ko, &As[cur ^ 1][(t + 256) << 3]);
            gl_lds16(Bg0 + ko, &Bs[cur ^ 1][t << 3]);
            gl_lds16(Bg1 + ko, &Bs[cur ^ 1][(t + 256) << 3]);
        }
        short8 af[4], bf[4];
        #pragma unroll
        for (int i = 0; i < 4; i++) {
            const int r = wr + (i << 4) + fr;
            af[i] = *(const short8*)&As[cur][(r << 5) + ((fq ^ ((r >> 1) & 3)) << 3)];
        }
        #pragma unroll
        for (int j = 0; j < 4; j++) {
            const int c = wc + (j << 4) + fr;
            bf[j] = *(const short8*)&Bs[cur][(c << 5) + ((fq ^ ((c >> 1) & 3)) << 3)];
        }
        #pragma unroll
        for (int i = 0; i < 4; i++)
            #pragma unroll
            for (int j = 0; j < 4; j++)
                acc[i][j] = __builtin_amdgcn_mfma_f32_16x16x32_bf16(af[i], bf[j], acc[i][j], 0, 0, 0);
        __syncthreads();
    }

    #pragma unroll
    for (int i = 0; i < 4; i++) {
        #pragma unroll
        for (int j = 0; j < 4; j++) {
            const int nl  = n0 + wc + (j << 4) + fr;
            const int mlb = m0 + wr + (i << 4) + (fq << 2);
            const float bsv = bias ? bias[nl] : 0.f;
            #pragma unroll
            for (int r = 0; r < 4; r++) {
                float v = acc[i][j][r] + bsv;
                if (relu) v = fmaxf(v, 0.f);
                long ci = (long)(mlb + r) * ldc + nl;
                if (Cf) Cf[ci] = v;
                if (Cb) Cb[ci] = f2bf(v);
            }
        }
    }
}

// ---------------------------------------------------------------------------
// Fused attention: block per (q-tile 64, head, batch), 4 waves x 16 q-rows.
// K/V tiles in LDS, double-buffered, ONE barrier per tile; sources
// pre-swizzled (c' = c ^ (row&7)) so swizzled ds_reads are conflict-free.
// ---------------------------------------------------------------------------
__global__ __launch_bounds__(256) void attn_fused(
    const u16* __restrict__ qkb, const u16* __restrict__ vt,
    const int* __restrict__ ids, u16* __restrict__ attc, int causal)
{
    __shared__ u16 Ks[2][4096];
    __shared__ u16 Vs[2][4096];
    __shared__ short Ps[4][16][72];
    const int t = threadIdx.x, lane = t & 63, w = t >> 6;
    const int fr = lane & 15, fq = lane >> 4;
    const int q0 = blockIdx.x << 6, h = blockIdx.y, b = blockIdx.z;

    const u16* qp = qkb + (long)(b * 512 + q0 + (w << 4) + fr) * 1024 + h * 64 + (fq << 3);
    short8 aq0 = *(const short8*)qp;
    short8 aq1 = *(const short8*)(qp + 32);

    const int sr = t >> 3, sc = (t & 7) ^ (sr & 7);
    const u16* kg0 = qkb + (long)(b * 512 + sr) * 1024 + 512 + h * 64 + (sc << 3);
    const u16* kg1 = kg0 + 32L * 1024;
    const u16* vg0 = vt + (long)b * S2W + (long)(h * 64 + sr) * 512 + (sc << 3);
    const u16* vg1 = vg0 + 32L * 512;

    unsigned pmask = 0;
    #pragma unroll
    for (int kt = 0; kt < 8; kt++)
        #pragma unroll
        for (int j = 0; j < 4; j++)
            if (ids[b * 512 + (kt << 6) + (j << 4) + fr] == PADID)
                pmask |= 1u << ((kt << 2) + j);

    float m[4], l[4]; f32x4 oc[4];
    #pragma unroll
    for (int r = 0; r < 4; r++) { m[r] = -INFINITY; l[r] = 0.f; oc[r] = (f32x4){0.f,0.f,0.f,0.f}; }

    const int lastkt = causal ? (q0 >> 6) : 7;
    auto stage = [&](int kt, int buf) {
        const long so = (long)(kt << 6);
        gl_lds16(kg0 + so * 1024, &Ks[buf][t << 3]);
        gl_lds16(kg1 + so * 1024, &Ks[buf][(t + 256) << 3]);
        gl_lds16(vg0 + so, &Vs[buf][t << 3]);
        gl_lds16(vg1 + so, &Vs[buf][(t + 256) << 3]);
    };
    stage(0, 0);
    __syncthreads();

    for (int kt = 0; kt <= lastkt; kt++) {
        const int cur = kt & 1;
        if (kt < lastkt) stage(kt + 1, cur ^ 1);

        f32x4 sc4[4];
        #pragma unroll
        for (int j = 0; j < 4; j++) sc4[j] = (f32x4){0.f,0.f,0.f,0.f};
        #pragma unroll
        for (int j = 0; j < 4; j++) {
            const int rr = (j << 4) + fr;
            short8 bk0 = *(const short8*)&Ks[cur][rr * 64 + ((fq ^ (rr & 7)) << 3)];
            short8 bk1 = *(const short8*)&Ks[cur][rr * 64 + (((fq | 4) ^ (rr & 7)) << 3)];
            sc4[j] = __builtin_amdgcn_mfma_f32_16x16x32_bf16(aq0, bk0, sc4[j], 0, 0, 0);
            sc4[j] = __builtin_amdgcn_mfma_f32_16x16x32_bf16(aq1, bk1, sc4[j], 0, 0, 0);
        }
        const int s0 = kt << 6;
        #pragma unroll
        for (int r = 0; r < 4; r++) {
            const int qa = q0 + (w << 4) + (fq << 2) + r;
            float mx = -INFINITY;
            #pragma unroll
            for (int j = 0; j < 4; j++) {
                bool msk = ((pmask >> ((kt << 2) + j)) & 1) ||
                           (causal && (s0 + (j << 4) + fr) > qa);
                float sv = msk ? -INFINITY : sc4[j][r] * 0.125f;
                sc4[j][r] = sv;
                mx = fmaxf(mx, sv);
            }
            mx = fmaxf(mx, __shfl_xor(mx, 1)); mx = fmaxf(mx, __shfl_xor(mx, 2));
            mx = fmaxf(mx, __shfl_xor(mx, 4)); mx = fmaxf(mx, __shfl_xor(mx, 8));
            float mnew  = fmaxf(m[r], mx);
            float scale = (mnew == -INFINITY) ? 1.f : __expf(m[r] - mnew);
            float ps = 0.f;
            #pragma unroll
            for (int j = 0; j < 4; j++) {
                float p = (sc4[j][r] == -INFINITY) ? 0.f : __expf(sc4[j][r] - mnew);
                sc4[j][r] = p; ps += p;
            }
            ps += __shfl_xor(ps, 1); ps += __shfl_xor(ps, 2);
            ps += __shfl_xor(ps, 4); ps += __shfl_xor(ps, 8);
            l[r] = l[r] * scale + ps;
            m[r] = mnew;
            #pragma unroll
            for (int j2 = 0; j2 < 4; j2++) oc[j2][r] *= scale;
        }
        #pragma unroll
        for (int r = 0; r < 4; r++)
            #pragma unroll
            for (int j = 0; j < 4; j++)
                Ps[w][(fq << 2) + r][(j << 4) + fr] = (short)f2bf(sc4[j][r]);
        #pragma unroll
        for (int kc = 0; kc < 2; kc++) {
            short8 pa = *(const short8*)&Ps[w][fr][(kc << 5) + (fq << 3)];
            #pragma unroll
            for (int j2 = 0; j2 < 4; j2++) {
                const int rd = (j2 << 4) + fr;
                const int cch = (((kc << 2) | fq) ^ (rd & 7));
                short8 bv = *(const short8*)&Vs[cur][rd * 64 + (cch << 3)];
                oc[j2] = __builtin_amdgcn_mfma_f32_16x16x32_bf16(pa, bv, oc[j2], 0, 0, 0);
            }
        }
        __syncthreads();
    }

    float inv[4];
    #pragma unroll
    for (int r = 0; r < 4; r++) inv[r] = (l[r] > 0.f) ? 1.f / l[r] : 0.f;
    #pragma unroll
    for (int j2 = 0; j2 < 4; j2++)
        #pragma unroll
        for (int r = 0; r < 4; r++)
            attc[(long)(b * 512 + q0 + (w << 4) + (fq << 2) + r) * 512 + h * 64 + (j2 << 4) + fr]
                = f2bf(oc[j2][r] * inv[r]);
}

// LayerNorm over D=512: 4 rows/block (wave per row). f32 in -> bf16 out.
__global__ __launch_bounds__(256) void ln_rows(
    const float* __restrict__ x, const float* __restrict__ g,
    const float* __restrict__ b, u16* __restrict__ out)
{
    int row  = blockIdx.x * 4 + (threadIdx.x >> 6);
    int lane = threadIdx.x & 63;
    const float* xr = x + (long)row * Dm;
    float v[8]; float s = 0.f;
    #pragma unroll
    for (int i = 0; i < 8; i++) { v[i] = xr[lane + (i << 6)]; s += v[i]; }
    #pragma unroll
    for (int o = 32; o > 0; o >>= 1) s += __shfl_xor(s, o);
    float mean = s * (1.f / 512.f);
    float q = 0.f;
    #pragma unroll
    for (int i = 0; i < 8; i++) { float d = v[i] - mean; q += d * d; }
    #pragma unroll
    for (int o = 32; o > 0; o >>= 1) q += __shfl_xor(q, o);
    float rinv = rsqrtf(q * (1.f / 512.f) + LNEPS);
    u16* orow = out + (long)row * Dm;
    #pragma unroll
    for (int i = 0; i < 8; i++) {
        int c = lane + (i << 6);
        orow[c] = f2bf((v[i] - mean) * rinv * g[c] + b[c]);
    }
}

// x[b,s,:] = embed[id]*sqrt(D) + PE(s,:)   (f32 in/out)
__global__ __launch_bounds__(256) void embed_pe(
    const int* __restrict__ ids, const float* __restrict__ emb,
    float* __restrict__ out)
{
    int idx = blockIdx.x * 256 + threadIdx.x;   // NTOK*512 = 2^20
    int d   = idx & 511;
    int tok = idx >> 9;
    int s   = tok & 511;
    int id  = ids[tok];
    float val = emb[(long)id * Dm + d] * 22.62741699796952f;     // sqrt(512)
    int i2 = d >> 1;
    float dv  = expf((float)(i2 << 1) * (-9.210340371976184f / 512.f));
    float ang = (float)s * dv;
    val += (d & 1) ? cosf(ang) : sinf(ang);
    out[idx] = val;
}

// ---------------------------------------------------------------------------
extern "C" void kernel_launch(void* const* d_in, const int* in_sizes, int n_in,
                              void* d_out, int out_size, void* d_ws, size_t ws_size,
                              hipStream_t stream)
{
    (void)in_sizes; (void)n_in; (void)out_size; (void)ws_size;
    const int*   src       = (const int*)d_in[0];
    const int*   tgt       = (const int*)d_in[1];
    const float* src_embed = (const float*)d_in[2];
    const float* tgt_embed = (const float*)d_in[3];
    const float* enc_b1  = (const float*)d_in[9];
    const float* enc_b2  = (const float*)d_in[11];
    const float* enc_ln1g = (const float*)d_in[12];
    const float* enc_ln1b = (const float*)d_in[13];
    const float* enc_ln2g = (const float*)d_in[14];
    const float* enc_ln2b = (const float*)d_in[15];
    const float* enc_lnfg = (const float*)d_in[16];
    const float* enc_lnfb = (const float*)d_in[17];
    const float* dec_b1  = (const float*)d_in[27];
    const float* dec_b2  = (const float*)d_in[29];
    const float* dec_ln1g = (const float*)d_in[30];
    const float* dec_ln1b = (const float*)d_in[31];
    const float* dec_ln2g = (const float*)d_in[32];
    const float* dec_ln2b = (const float*)d_in[33];
    const float* dec_ln3g = (const float*)d_in[34];
    const float* dec_ln3b = (const float*)d_in[35];
    const float* dec_lnfg = (const float*)d_in[36];
    const float* dec_lnfb = (const float*)d_in[37];
    const float* out_b  = (const float*)d_in[39];

    char* wp = (char*)d_ws;
    auto carve = [&](size_t nbytes) {
        void* p = (void*)wp; wp += (nbytes + 255) & ~(size_t)255; return p;
    };

    const long nW = (long)NLay * S2W;
    const long nF = (long)NLay * DFFm * Dm;
    const long nO = 32000L * Dm;

    u16* Wb[12];
    for (int i = 0; i < 12; i++) Wb[i] = (u16*)carve((size_t)nW * 2);
    u16* w1E  = (u16*)carve((size_t)nF * 2);
    u16* w2E  = (u16*)carve((size_t)nF * 2);
    u16* w1D  = (u16*)carve((size_t)nF * 2);
    u16* w2D  = (u16*)carve((size_t)nF * 2);
    u16* outW = (u16*)carve((size_t)nO * 2);

    float* x  = (float*)carve((size_t)NTOK * Dm * 4);
    float* y  = (float*)carve((size_t)NTOK * Dm * 4);
    u16* nrm  = (u16*)carve((size_t)NTOK * Dm * 2);
    u16* qkb  = (u16*)carve((size_t)NTOK * 1024 * 2);
    u16* vt   = (u16*)carve((size_t)Bb * Dm * 512 * 2);
    u16* attc = (u16*)carve((size_t)NTOK * Dm * 2);
    u16* h1   = (u16*)carve((size_t)NTOK * DFFm * 2);
    u16* memn = (u16*)carve((size_t)NTOK * Dm * 2);

    // d_in indices for the 12 attn weight tensors, matching Wb order:
    // eWq eWk eWv eWo | sWq sWk sWv sWo | cWq cWk cWv cWo
    const int wi[12] = {4, 5, 6, 7, 18, 19, 20, 21, 22, 23, 24, 25};
    CvtJobs jobs;
    for (int i = 0; i < 12; i++) {
        jobs.s[i] = (const float*)d_in[wi[i]]; jobs.d[i] = Wb[i]; jobs.n4[i] = nW >> 2;
    }
    jobs.s[12] = (const float*)d_in[8];  jobs.d[12] = w1E;  jobs.n4[12] = nF >> 2;
    jobs.s[13] = (const float*)d_in[10]; jobs.d[13] = w2E;  jobs.n4[13] = nF >> 2;
    jobs.s[14] = (const float*)d_in[26]; jobs.d[14] = w1D;  jobs.n4[14] = nF >> 2;
    jobs.s[15] = (const float*)d_in[28]; jobs.d[15] = w2D;  jobs.n4[15] = nF >> 2;
    jobs.s[16] = (const float*)d_in[38]; jobs.d[16] = outW; jobs.n4[16] = nO >> 2;
    cvt_many<<<dim3(512, 17), 256, 0, stream>>>(jobs);

    const int BIG = 1 << 28;
    u16 *eWq = Wb[0], *eWk = Wb[1], *eWv = Wb[2], *eWo = Wb[3];
    u16 *sWq = Wb[4], *sWk = Wb[5], *sWv = Wb[6], *sWo = Wb[7];
    u16 *cWq = Wb[8], *cWk = Wb[9], *cWv = Wb[10], *cWo = Wb[11];

    // ---------------- Encoder ----------------
    embed_pe<<<4096, 256, 0, stream>>>(src, src_embed, x);
    for (int l = 0; l < NLay; l++) {
        const size_t wo = (size_t)l * S2W;
        ln_rows<<<512, 256, 0, stream>>>(x, enc_ln1g + l * Dm, enc_ln1b + l * Dm, nrm);
        // fused QKV: parts -> qkb[:,0:512]=Q, qkb[:,512:1024]=K, vt=V^T
        gemm_bt<<<dim3(24, 32, 1), 256, 0, stream>>>(nrm, nrm, nrm, 512,
            eWq + wo, eWk + wo, eWv + wo, 512,
            nullptr, qkb, 1024, nullptr, 0, 512, 1, 1024, 0, vt);
        attn_fused<<<dim3(8, Hh, Bb), 256, 0, stream>>>(qkb, vt, src, attc, 0);
        // x += attc @ Wo^T   (split-K=2, atomic)
        gemm_bt<<<dim3(8, 32, 2), 256, 0, stream>>>(attc, attc, attc, 512,
            eWo + wo, nullptr, nullptr, 512,
            x, nullptr, 512, nullptr, 0, 256, 2, BIG, 0, nullptr);
        ln_rows<<<512, 256, 0, stream>>>(x, enc_ln2g + l * Dm, enc_ln2b + l * Dm, nrm);
        // h1 = relu(nrm @ w1^T + b1)
        gemm_bt<<<dim3(32, 32, 1), 256, 0, stream>>>(nrm, nrm, nrm, 512,
            w1E + (size_t)l * DFFm * Dm, nullptr, nullptr, 512,
            nullptr, h1, DFFm, enc_b1 + l * DFFm, 1, 512, 1, BIG, 0, nullptr);
        // x += h1 @ w2^T + b2   (split-K=4, atomic)
        gemm_bt<<<dim3(8, 32, 4), 256, 0, stream>>>(h1, h1, h1, DFFm,
            w2E + (size_t)l * Dm * DFFm, nullptr, nullptr, DFFm,
            x, nullptr, 512, enc_b2 + l * Dm, 0, 512, 4, BIG, 0, nullptr);
    }
    ln_rows<<<512, 256, 0, stream>>>(x, enc_lnfg, enc_lnfb, memn);

    // ---------------- Decoder ----------------
    embed_pe<<<4096, 256, 0, stream>>>(tgt, tgt_embed, y);
    for (int l = 0; l < NLay; l++) {
        const size_t wo = (size_t)l * S2W;
        // self-attention (causal + tgt pad)
        ln_rows<<<512, 256, 0, stream>>>(y, dec_ln1g + l * Dm, dec_ln1b + l * Dm, nrm);
        gemm_bt<<<dim3(24, 32, 1), 256, 0, stream>>>(nrm, nrm, nrm, 512,
            sWq + wo, sWk + wo, sWv + wo, 512,
            nullptr, qkb, 1024, nullptr, 0, 512, 1, 1024, 0, vt);
        attn_fused<<<dim3(8, Hh, Bb), 256, 0, stream>>>(qkb, vt, tgt, attc, 1);
        gemm_bt<<<dim3(8, 32, 2), 256, 0, stream>>>(attc, attc, attc, 512,
            sWo + wo, nullptr, nullptr, 512,
            y, nullptr, 512, nullptr, 0, 256, 2, BIG, 0, nullptr);
        // cross-attention: merged Q(from y-norm) + K/V (from encoder memory)
        ln_rows<<<512, 256, 0, stream>>>(y, dec_ln2g + l * Dm, dec_ln2b + l * Dm, nrm);
        gemm_bt<<<dim3(24, 32, 1), 256, 0, stream>>>(nrm, memn, memn, 512,
            cWq + wo, cWk + wo, cWv + wo, 512,
            nullptr, qkb, 1024, nullptr, 0, 512, 1, 1024, 0, vt);
        attn_fused<<<dim3(8, Hh, Bb), 256, 0, stream>>>(qkb, vt, src, attc, 0);
        gemm_bt<<<dim3(8, 32, 2), 256, 0, stream>>>(attc, attc, attc, 512,
            cWo + wo, nullptr, nullptr, 512,
            y, nullptr, 512, nullptr, 0, 256, 2, BIG, 0, nullptr);
        // FFN
        ln_rows<<<512, 256, 0, stream>>>(y, dec_ln3g + l * Dm, dec_ln3b + l * Dm, nrm);
        gemm_bt<<<dim3(32, 32, 1), 256, 0, stream>>>(nrm, nrm, nrm, 512,
            w1D + (size_t)l * DFFm * Dm, nullptr, nullptr, 512,
            nullptr, h1, DFFm, dec_b1 + l * DFFm, 1, 512, 1, BIG, 0, nullptr);
        gemm_bt<<<dim3(8, 32, 4), 256, 0, stream>>>(h1, h1, h1, DFFm,
            w2D + (size_t)l * Dm * DFFm, nullptr, nullptr, DFFm,
            y, nullptr, 512, dec_b2 + l * Dm, 0, 512, 4, BIG, 0, nullptr);
    }
    ln_rows<<<512, 256, 0, stream>>>(y, dec_lnfg, dec_lnfb, nrm);

    // final projection to vocab: [2048][32000] f32 out
    gemm_big<<<dim3(250, 16), 256, 0, stream>>>(nrm, 512, outW, 512,
        (float*)d_out, nullptr, 32000, out_b, 0, 512);
}